// Round 1
// baseline (1791.676 us; speedup 1.0000x reference)
//
#include <hip/hip_runtime.h>

#define F_IN 33
#define C 128      // F_OUT
#define GROWS 8    // rows per block in gat_gemm
#define BROWS 8    // rows per block in blend

// ---- CSR build -------------------------------------------------------------

__global__ void count_kernel(const int* __restrict__ col, const float* __restrict__ w,
                             int* __restrict__ cnt, float* __restrict__ deg, int E) {
  int e = blockIdx.x * blockDim.x + threadIdx.x;
  if (e < E) {
    int c = col[e];
    atomicAdd(&cnt[c], 1);
    atomicAdd(&deg[c], w[e]);
  }
}

// exclusive scan of cnt[0..n) -> off[0..n), single block of 1024 threads
__global__ void scan_kernel(const int* __restrict__ cnt, int* __restrict__ off, int n) {
  __shared__ int lds[1024];
  __shared__ int carry;
  int tid = threadIdx.x;
  if (tid == 0) carry = 0;
  __syncthreads();
  for (int base = 0; base < n; base += 1024) {
    int i = base + tid;
    int v = (i < n) ? cnt[i] : 0;
    lds[tid] = v;
    __syncthreads();
    for (int ofs = 1; ofs < 1024; ofs <<= 1) {
      int t = (tid >= ofs) ? lds[tid - ofs] : 0;
      __syncthreads();
      lds[tid] += t;
      __syncthreads();
    }
    if (i < n) off[i] = carry + lds[tid] - v;   // exclusive
    __syncthreads();
    if (tid == 0) carry += lds[1023];
    __syncthreads();
  }
}

__global__ void scatter_kernel(const int* __restrict__ row, const int* __restrict__ col,
                               const float* __restrict__ w, const int* __restrict__ off,
                               int* __restrict__ cur, int* __restrict__ srow,
                               float* __restrict__ sw, int E) {
  int e = blockIdx.x * blockDim.x + threadIdx.x;
  if (e < E) {
    int c = col[e];
    int p = off[c] + atomicAdd(&cur[c], 1);
    srow[p] = row[e];
    sw[p] = w[e];
  }
}

__global__ void dinv_kernel(const float* __restrict__ deg, float* __restrict__ dinv, int N) {
  int i = blockIdx.x * blockDim.x + threadIdx.x;
  if (i < N) dinv[i] = rsqrtf(deg[i] + 1.0f);   // +1 = self-loop weight
}

// ---- GCN -------------------------------------------------------------------

// x [N,33] @ W [33,128] -> out [N,128]; W (16.5 KB) stays L1-resident.
__global__ void gemm33_kernel(const float* __restrict__ x, const float* __restrict__ W,
                              float* __restrict__ out, int N) {
  int n = blockIdx.x;
  int t = threadIdx.x;   // 0..127
  __shared__ float xr[F_IN];
  if (t < F_IN) xr[t] = x[n * F_IN + t];
  __syncthreads();
  float acc = 0.f;
  #pragma unroll
  for (int k = 0; k < F_IN; k++) acc += xr[k] * W[k * C + t];
  out[n * C + t] = acc;
}

// out[c] = relu( sum_{e->c} dinv[r]*w*dinv[c]*xl[r] + dinv[c]^2*xl[c] + b )
__global__ void gcn_agg_kernel(const float* __restrict__ xl, const int* __restrict__ off,
                               const int* __restrict__ srow, const float* __restrict__ sw,
                               const float* __restrict__ dinv, const float* __restrict__ b,
                               float* __restrict__ out) {
  int c = blockIdx.x;
  int t = threadIdx.x;   // 0..127
  float dc = dinv[c];
  float acc = dc * dc * xl[c * C + t];          // self loop, weight 1
  int p1 = off[c + 1];
  for (int p = off[c]; p < p1; p++) {
    int r = srow[p];
    float nm = dinv[r] * sw[p] * dc;
    acc += nm * xl[r * C + t];
  }
  acc += b[t];
  out[c * C + t] = fmaxf(acc, 0.f);
}

// ---- GAT -------------------------------------------------------------------

// x [N,128] @ W [128,256] -> xl [N,256]; 8 rows/block so W streams from L2
// once per 8 nodes instead of once per node.
__global__ void gat_gemm_kernel(const float* __restrict__ x, const float* __restrict__ W,
                                float* __restrict__ xl, int N) {
  int n0 = blockIdx.x * GROWS;
  int j = threadIdx.x;   // 0..255
  __shared__ float xr[GROWS * C];
  for (int i = j; i < GROWS * C; i += 256) {
    int n = n0 + i / C;
    xr[i] = (n < N) ? x[n0 * C + i] : 0.f;
  }
  __syncthreads();
  float acc[GROWS];
  #pragma unroll
  for (int r = 0; r < GROWS; r++) acc[r] = 0.f;
  #pragma unroll 4
  for (int k = 0; k < C; k++) {
    float wv = W[k * 2 * C + j];
    #pragma unroll
    for (int r = 0; r < GROWS; r++) acc[r] += xr[r * C + k] * wv;
  }
  for (int r = 0; r < GROWS; r++) {
    int n = n0 + r;
    if (n < N) xl[(size_t)n * 2 * C + j] = acc[r];
  }
}

// per-node attention dots: asrc[n,h] = sum_c xl[n,h,c]*att_s[h,c] (same for adst)
__global__ void att_dots_kernel(const float* __restrict__ xl, const float* __restrict__ as,
                                const float* __restrict__ ad, float* __restrict__ asrc,
                                float* __restrict__ adst) {
  int n = blockIdx.x;
  int j = threadIdx.x;   // 0..255 = h*128 + c
  float v = xl[(size_t)n * 2 * C + j];
  __shared__ float red[256];
  red[j] = v * as[j];
  __syncthreads();
  for (int s = 64; s > 0; s >>= 1) {
    if ((j & (C - 1)) < s) red[j] += red[j + s];
    __syncthreads();
  }
  if ((j & (C - 1)) == 0) asrc[n * 2 + (j >> 7)] = red[j];
  __syncthreads();
  red[j] = v * ad[j];
  __syncthreads();
  for (int s = 64; s > 0; s >>= 1) {
    if ((j & (C - 1)) < s) red[j] += red[j + s];
    __syncthreads();
  }
  if ((j & (C - 1)) == 0) adst[n * 2 + (j >> 7)] = red[j];
}

// online edge-softmax + aggregate + head-mean (+optional relu)
__global__ void gat_agg_kernel(const float* __restrict__ xl, const float* __restrict__ asrc,
                               const float* __restrict__ adst, const int* __restrict__ off,
                               const int* __restrict__ srow, const float* __restrict__ b,
                               float* __restrict__ out, int relu) {
  int c = blockIdx.x;
  int j = threadIdx.x;   // 0..255; h = j>>7
  int h = j >> 7;
  float adc = adst[c * 2 + h];
  // self loop first: e0, running (m, s, acc)
  float e0 = asrc[c * 2 + h] + adc;
  e0 = (e0 > 0.f) ? e0 : 0.2f * e0;
  float m = e0;
  float s = 1.0f;                                  // exp(e0 - m)
  float acc = xl[(size_t)c * 2 * C + j];
  int p1 = off[c + 1];
  for (int p = off[c]; p < p1; p++) {
    int r = srow[p];
    float e = asrc[r * 2 + h] + adc;
    e = (e > 0.f) ? e : 0.2f * e;
    float mn = fmaxf(m, e);
    float sc = __expf(m - mn);
    float pe = __expf(e - mn);
    s = s * sc + pe;
    acc = acc * sc + pe * xl[(size_t)r * 2 * C + j];
    m = mn;
  }
  __shared__ float red[256];
  red[j] = acc / s;
  __syncthreads();
  if (j < C) {
    float v = 0.5f * (red[j] + red[j + C]) + b[j];
    if (relu) v = fmaxf(v, 0.f);
    out[c * C + j] = v;
  }
}

// ---- gated blend: out = z*xt + (1-z)*x, z = sigmoid(xt@fc1 + x@fc2 + biases)
__global__ void blend_kernel(const float* __restrict__ xt, const float* __restrict__ x,
                             const float* __restrict__ fc1W, const float* __restrict__ fc1b,
                             const float* __restrict__ fc2W, const float* __restrict__ fc2b,
                             const float* __restrict__ pb, float* __restrict__ out, int N) {
  int n0 = blockIdx.x * BROWS;
  int j = threadIdx.x;   // 0..127
  __shared__ float xtr[BROWS * C];
  __shared__ float xr[BROWS * C];
  for (int i = j; i < BROWS * C; i += C) {
    int n = n0 + i / C;
    xtr[i] = (n < N) ? xt[n0 * C + i] : 0.f;
    xr[i]  = (n < N) ? x[n0 * C + i] : 0.f;
  }
  __syncthreads();
  float s1[BROWS], s2[BROWS];
  #pragma unroll
  for (int r = 0; r < BROWS; r++) { s1[r] = 0.f; s2[r] = 0.f; }
  #pragma unroll 2
  for (int k = 0; k < C; k++) {
    float w1 = fc1W[k * C + j];
    float w2 = fc2W[k * C + j];
    #pragma unroll
    for (int r = 0; r < BROWS; r++) {
      s1[r] += xtr[r * C + k] * w1;
      s2[r] += xr[r * C + k] * w2;
    }
  }
  float bb = fc1b[j] + fc2b[j] + pb[j];
  for (int r = 0; r < BROWS; r++) {
    int n = n0 + r;
    if (n < N) {
      float t = s1[r] + s2[r] + bb;
      float z = 1.f / (1.f + __expf(-t));
      out[n * C + j] = z * xtr[r * C + j] + (1.f - z) * xr[r * C + j];
    }
  }
}

// ---- launch ----------------------------------------------------------------

extern "C" void kernel_launch(void* const* d_in, const int* in_sizes, int n_in,
                              void* d_out, int out_size, void* d_ws, size_t ws_size,
                              hipStream_t stream) {
  const float* x_in  = (const float*)d_in[0];
  const int*   ei    = (const int*)d_in[1];
  const float* ew    = (const float*)d_in[2];
  const float* gcn_W = (const float*)d_in[3];
  const float* gcn_b = (const float*)d_in[4];
  const float* g1_W  = (const float*)d_in[5];
  const float* g1_as = (const float*)d_in[6];
  const float* g1_ad = (const float*)d_in[7];
  const float* g1_b  = (const float*)d_in[8];
  const float* g2_W  = (const float*)d_in[9];
  const float* g2_as = (const float*)d_in[10];
  const float* g2_ad = (const float*)d_in[11];
  const float* g2_b  = (const float*)d_in[12];
  const float* fc1_W = (const float*)d_in[13];
  const float* fc1_b = (const float*)d_in[14];
  const float* fc2_W = (const float*)d_in[15];
  const float* fc2_b = (const float*)d_in[16];
  const float* pb    = (const float*)d_in[17];

  const int N = in_sizes[0] / F_IN;
  const int E = in_sizes[2];
  const int* row = ei;
  const int* col = ei + E;

  char* ws = (char*)d_ws;
  size_t o = 0;
  auto alloc = [&](size_t bytes) -> void* {
    void* p = ws + o;
    o += (bytes + 255) & ~(size_t)255;
    return p;
  };
  int*   cnt  = (int*)alloc((size_t)(N + 1) * 4);
  int*   cur  = (int*)alloc((size_t)N * 4);
  float* deg  = (float*)alloc((size_t)N * 4);
  size_t zero_bytes = o;                     // cnt+cur+deg live at ws start
  int*   off  = (int*)alloc((size_t)(N + 1) * 4);
  float* dinv = (float*)alloc((size_t)N * 4);
  int*   srow = (int*)alloc((size_t)E * 4);
  float* sw   = (float*)alloc((size_t)E * 4);
  float* A    = (float*)alloc((size_t)N * C * 4);      // gcn xl / gat xt
  float* H    = (float*)alloc((size_t)N * C * 4);      // running x
  float* XL   = (float*)alloc((size_t)N * 2 * C * 4);  // gat xl [N,2,128]
  float* asrc = (float*)alloc((size_t)N * 2 * 4);
  float* adst = (float*)alloc((size_t)N * 2 * 4);
  (void)ws_size; (void)n_in; (void)out_size;

  hipMemsetAsync(d_ws, 0, zero_bytes, stream);

  const int tb = 256;
  count_kernel<<<(E + tb - 1) / tb, tb, 0, stream>>>(col, ew, cnt, deg, E);
  scan_kernel<<<1, 1024, 0, stream>>>(cnt, off, N + 1);
  scatter_kernel<<<(E + tb - 1) / tb, tb, 0, stream>>>(row, col, ew, off, cur, srow, sw, E);
  dinv_kernel<<<(N + tb - 1) / tb, tb, 0, stream>>>(deg, dinv, N);

  // GCN + ReLU
  gemm33_kernel<<<N, C, 0, stream>>>(x_in, gcn_W, A, N);
  gcn_agg_kernel<<<N, C, 0, stream>>>(A, off, srow, sw, dinv, gcn_b, H);

  // GAT layer 1 (+ReLU) + gated blend (in-place into H)
  gat_gemm_kernel<<<(N + GROWS - 1) / GROWS, 256, 0, stream>>>(H, g1_W, XL, N);
  att_dots_kernel<<<N, 256, 0, stream>>>(XL, g1_as, g1_ad, asrc, adst);
  gat_agg_kernel<<<N, 256, 0, stream>>>(XL, asrc, adst, off, srow, g1_b, A, 1);
  blend_kernel<<<(N + BROWS - 1) / BROWS, C, 0, stream>>>(A, H, fc1_W, fc1_b, fc2_W, fc2_b, pb, H, N);

  // GAT layer 2 (no ReLU) + gated blend into d_out
  gat_gemm_kernel<<<(N + GROWS - 1) / GROWS, 256, 0, stream>>>(H, g2_W, XL, N);
  att_dots_kernel<<<N, 256, 0, stream>>>(XL, g2_as, g2_ad, asrc, adst);
  gat_agg_kernel<<<N, 256, 0, stream>>>(XL, asrc, adst, off, srow, g2_b, A, 0);
  blend_kernel<<<(N + BROWS - 1) / BROWS, C, 0, stream>>>(A, H, fc1_W, fc1_b, fc2_W, fc2_b, pb, (float*)d_out, N);
}

// Round 2
// 1565.201 us; speedup vs baseline: 1.1447x; 1.1447x over previous
//
#include <hip/hip_runtime.h>

#define F_IN 33
#define C 128      // F_OUT
#define GROWS 16   // rows per block in gat_gemm
#define BROWS 16   // rows per block in blend
#define MROWS 8    // rows per block in gemm33

// ---- CSR build -------------------------------------------------------------

__global__ void count_kernel(const int* __restrict__ col, const float* __restrict__ w,
                             int* __restrict__ cnt, float* __restrict__ deg, int E) {
  int e = blockIdx.x * blockDim.x + threadIdx.x;
  if (e < E) {
    int c = col[e];
    atomicAdd(&cnt[c], 1);
    atomicAdd(&deg[c], w[e]);
  }
}

// hierarchical exclusive scan: scan1 (1024 elems/block) -> scan2 (block sums) -> scan3 (add)
__global__ void scan1_kernel(const int* __restrict__ cnt, int* __restrict__ out,
                             int* __restrict__ bsum, int n) {
  __shared__ int lds[256];
  int t = threadIdx.x;
  int base = blockIdx.x * 1024 + t * 4;
  int v0 = (base + 0 < n) ? cnt[base + 0] : 0;
  int v1 = (base + 1 < n) ? cnt[base + 1] : 0;
  int v2 = (base + 2 < n) ? cnt[base + 2] : 0;
  int v3 = (base + 3 < n) ? cnt[base + 3] : 0;
  int tot = v0 + v1 + v2 + v3;
  lds[t] = tot;
  __syncthreads();
  for (int o = 1; o < 256; o <<= 1) {
    int x = (t >= o) ? lds[t - o] : 0;
    __syncthreads();
    lds[t] += x;
    __syncthreads();
  }
  int excl = lds[t] - tot;
  if (t == 255) bsum[blockIdx.x] = lds[255];
  if (base + 0 < n) out[base + 0] = excl;
  if (base + 1 < n) out[base + 1] = excl + v0;
  if (base + 2 < n) out[base + 2] = excl + v0 + v1;
  if (base + 3 < n) out[base + 3] = excl + v0 + v1 + v2;
}

__global__ void scan2_kernel(int* __restrict__ bsum, int nb) {
  __shared__ int lds[256];
  int t = threadIdx.x;
  int v = (t < nb) ? bsum[t] : 0;
  lds[t] = v;
  __syncthreads();
  for (int o = 1; o < 256; o <<= 1) {
    int x = (t >= o) ? lds[t - o] : 0;
    __syncthreads();
    lds[t] += x;
    __syncthreads();
  }
  if (t < nb) bsum[t] = lds[t] - v;   // exclusive
}

__global__ void scan3_kernel(int* __restrict__ off, const int* __restrict__ bsum, int n) {
  int i = blockIdx.x * blockDim.x + threadIdx.x;
  if (i < n) off[i] += bsum[i >> 10];
}

__global__ void dinv_kernel(const float* __restrict__ deg, float* __restrict__ dinv, int N) {
  int i = blockIdx.x * blockDim.x + threadIdx.x;
  if (i < N) dinv[i] = rsqrtf(deg[i] + 1.0f);   // +1 = self-loop weight
}

// scatter; sw[p] = dinv[row]*w so gcn_agg needs no per-edge dinv gather
__global__ void scatter_kernel(const int* __restrict__ row, const int* __restrict__ col,
                               const float* __restrict__ w, const int* __restrict__ off,
                               const float* __restrict__ dinv, int* __restrict__ cur,
                               int* __restrict__ srow, float* __restrict__ sw, int E) {
  int e = blockIdx.x * blockDim.x + threadIdx.x;
  if (e < E) {
    int c = col[e];
    int r = row[e];
    int p = off[c] + atomicAdd(&cur[c], 1);
    srow[p] = r;
    sw[p] = dinv[r] * w[e];
  }
}

// ---- GCN -------------------------------------------------------------------

// x [N,33] @ W [33,128] -> out [N,128]; MROWS rows per block of 128 threads
__global__ void gemm33_kernel(const float* __restrict__ x, const float* __restrict__ W,
                              float* __restrict__ out, int N) {
  int n0 = blockIdx.x * MROWS;
  int t = threadIdx.x;   // 0..127
  __shared__ float xr[MROWS * F_IN];
  for (int i = t; i < MROWS * F_IN; i += 128) {
    int idx = n0 * F_IN + i;
    xr[i] = (idx < N * F_IN) ? x[idx] : 0.f;
  }
  __syncthreads();
  float acc[MROWS];
  #pragma unroll
  for (int r = 0; r < MROWS; r++) acc[r] = 0.f;
  #pragma unroll
  for (int k = 0; k < F_IN; k++) {
    float wv = W[k * C + t];
    #pragma unroll
    for (int r = 0; r < MROWS; r++) acc[r] += xr[r * F_IN + k] * wv;
  }
  for (int r = 0; r < MROWS; r++) {
    int n = n0 + r;
    if (n < N) out[n * C + t] = acc[r];
  }
}

// 4 nodes per block, one wave each; float2 per lane (64*8B = 512B row)
__global__ void gcn_agg_kernel(const float* __restrict__ xl, const int* __restrict__ off,
                               const int* __restrict__ srow, const float* __restrict__ sw,
                               const float* __restrict__ dinv, const float* __restrict__ b,
                               float* __restrict__ out, int N) {
  int c = blockIdx.x * 4 + (threadIdx.x >> 6);
  if (c >= N) return;
  int l = threadIdx.x & 63;
  const float2* xv = (const float2*)xl;
  float dc = dinv[c];
  float2 xc = xv[(size_t)c * 64 + l];
  float a0x = dc * xc.x, a0y = dc * xc.y;   // *dc at end -> dc^2 * x_c
  float a1x = 0.f, a1y = 0.f;
  int p = off[c], p1 = off[c + 1];
  for (; p + 2 <= p1; p += 2) {
    int r0 = srow[p], r1 = srow[p + 1];
    float w0 = sw[p], w1 = sw[p + 1];
    float2 v0 = xv[(size_t)r0 * 64 + l];
    float2 v1 = xv[(size_t)r1 * 64 + l];
    a0x += w0 * v0.x; a0y += w0 * v0.y;
    a1x += w1 * v1.x; a1y += w1 * v1.y;
  }
  if (p < p1) {
    float w0 = sw[p];
    float2 v0 = xv[(size_t)srow[p] * 64 + l];
    a0x += w0 * v0.x; a0y += w0 * v0.y;
  }
  float2 bb = ((const float2*)b)[l];
  float2 o;
  o.x = fmaxf(dc * (a0x + a1x) + bb.x, 0.f);
  o.y = fmaxf(dc * (a0y + a1y) + bb.y, 0.f);
  ((float2*)out)[(size_t)c * 64 + l] = o;
}

// ---- GAT -------------------------------------------------------------------

// x [N,128] @ W [128,256] -> xl [N,256]; fused per-node attention dots.
__global__ void gat_gemm_kernel(const float* __restrict__ x, const float* __restrict__ W,
                                const float* __restrict__ as, const float* __restrict__ ad,
                                float* __restrict__ xl, float* __restrict__ asrc,
                                float* __restrict__ adst, int N) {
  int n0 = blockIdx.x * GROWS;
  int j = threadIdx.x;   // 0..255
  __shared__ float xr[GROWS * C];          // 8 KB
  __shared__ float xls[GROWS * 264];       // ~16.5 KB, stride 264 kills bank conflicts
  for (int i = j; i < GROWS * C; i += 256) {
    int n = n0 + i / C;
    xr[i] = (n < N) ? x[n0 * C + i] : 0.f;
  }
  __syncthreads();
  float acc[GROWS];
  #pragma unroll
  for (int r = 0; r < GROWS; r++) acc[r] = 0.f;
  #pragma unroll 4
  for (int k = 0; k < C; k++) {
    float wv = W[k * 2 * C + j];
    #pragma unroll
    for (int r = 0; r < GROWS; r++) acc[r] += xr[r * C + k] * wv;
  }
  for (int r = 0; r < GROWS; r++) {
    int n = n0 + r;
    if (n < N) xl[(size_t)n * 2 * C + j] = acc[r];
    xls[r * 264 + j] = acc[r];
  }
  __syncthreads();
  // 32 teams of 8 threads: team = (r,h); each thread sums 16 strided elements
  int team = j >> 3, sub = j & 7;
  int r = team >> 1, h = team & 1;
  float sa = 0.f, sd = 0.f;
  for (int k = sub; k < C; k += 8) {
    float v = xls[r * 264 + h * C + k];
    sa += v * as[h * C + k];
    sd += v * ad[h * C + k];
  }
  #pragma unroll
  for (int o = 4; o > 0; o >>= 1) {
    sa += __shfl_down(sa, o);
    sd += __shfl_down(sd, o);
  }
  if (sub == 0 && n0 + r < N) {
    asrc[(n0 + r) * 2 + h] = sa;
    adst[(n0 + r) * 2 + h] = sd;
  }
}

// edge softmax phase 1: per-node max, alpha = exp(e-m), denominator, self weight.
// 4 nodes per block, one wave each.
__global__ void att_edge_kernel(const float* __restrict__ asrc, const float* __restrict__ adst,
                                const int* __restrict__ off, const int* __restrict__ srow,
                                float* __restrict__ alpha, float* __restrict__ sarr,
                                float* __restrict__ selfw, int N) {
  int c = blockIdx.x * 4 + (threadIdx.x >> 6);
  if (c >= N) return;
  int lane = threadIdx.x & 63;
  float ad0 = adst[c * 2 + 0], ad1 = adst[c * 2 + 1];
  int p0 = off[c], p1 = off[c + 1];
  float e00 = asrc[c * 2 + 0] + ad0; e00 = e00 > 0.f ? e00 : 0.2f * e00;
  float e01 = asrc[c * 2 + 1] + ad1; e01 = e01 > 0.f ? e01 : 0.2f * e01;
  float m0 = e00, m1 = e01;
  for (int p = p0 + lane; p < p1; p += 64) {
    int r = srow[p];
    float e0 = asrc[r * 2 + 0] + ad0; e0 = e0 > 0.f ? e0 : 0.2f * e0;
    float e1 = asrc[r * 2 + 1] + ad1; e1 = e1 > 0.f ? e1 : 0.2f * e1;
    m0 = fmaxf(m0, e0); m1 = fmaxf(m1, e1);
  }
  #pragma unroll
  for (int o = 32; o > 0; o >>= 1) {
    m0 = fmaxf(m0, __shfl_xor(m0, o));
    m1 = fmaxf(m1, __shfl_xor(m1, o));
  }
  float s0 = 0.f, s1 = 0.f;
  for (int p = p0 + lane; p < p1; p += 64) {
    int r = srow[p];
    float e0 = asrc[r * 2 + 0] + ad0; e0 = e0 > 0.f ? e0 : 0.2f * e0;
    float e1 = asrc[r * 2 + 1] + ad1; e1 = e1 > 0.f ? e1 : 0.2f * e1;
    float a0 = __expf(e0 - m0), a1 = __expf(e1 - m1);
    ((float2*)alpha)[p] = make_float2(a0, a1);
    s0 += a0; s1 += a1;
  }
  #pragma unroll
  for (int o = 32; o > 0; o >>= 1) {
    s0 += __shfl_xor(s0, o);
    s1 += __shfl_xor(s1, o);
  }
  float w0 = __expf(e00 - m0), w1 = __expf(e01 - m1);
  if (lane == 0) {
    sarr[c * 2 + 0] = s0 + w0;
    sarr[c * 2 + 1] = s1 + w1;
    selfw[c * 2 + 0] = w0;
    selfw[c * 2 + 1] = w1;
  }
}

// edge softmax phase 2: pure-fma aggregate. 4 nodes/block, 1 wave each,
// float4 per lane (64*16B = 1024B row = both heads); shfl head-mean.
__global__ void gat_agg2_kernel(const float* __restrict__ xl, const float* __restrict__ alpha,
                                const float* __restrict__ sarr, const float* __restrict__ selfw,
                                const int* __restrict__ off, const int* __restrict__ srow,
                                const float* __restrict__ b, float* __restrict__ out,
                                int relu, int N) {
  int c = blockIdx.x * 4 + (threadIdx.x >> 6);
  if (c >= N) return;
  int l = threadIdx.x & 63;
  int h = l >> 5;
  const float4* xv = (const float4*)xl;   // row = 64 float4
  float4 xc = xv[(size_t)c * 64 + l];
  float swt = selfw[c * 2 + h];
  float a0x = swt * xc.x, a0y = swt * xc.y, a0z = swt * xc.z, a0w = swt * xc.w;
  float a1x = 0.f, a1y = 0.f, a1z = 0.f, a1w = 0.f;
  int p = off[c], p1 = off[c + 1];
  for (; p + 2 <= p1; p += 2) {
    int r0 = srow[p], r1 = srow[p + 1];
    float al0 = alpha[p * 2 + h], al1 = alpha[(p + 1) * 2 + h];
    float4 v0 = xv[(size_t)r0 * 64 + l];
    float4 v1 = xv[(size_t)r1 * 64 + l];
    a0x += al0 * v0.x; a0y += al0 * v0.y; a0z += al0 * v0.z; a0w += al0 * v0.w;
    a1x += al1 * v1.x; a1y += al1 * v1.y; a1z += al1 * v1.z; a1w += al1 * v1.w;
  }
  if (p < p1) {
    float al = alpha[p * 2 + h];
    float4 v = xv[(size_t)srow[p] * 64 + l];
    a0x += al * v.x; a0y += al * v.y; a0z += al * v.z; a0w += al * v.w;
  }
  float inv_s = 1.f / sarr[c * 2 + h];
  float vx = (a0x + a1x) * inv_s, vy = (a0y + a1y) * inv_s;
  float vz = (a0z + a1z) * inv_s, vw = (a0w + a1w) * inv_s;
  // head mean: lane l (<32, head0) pairs with l+32 (head1), same feature block
  float ox = 0.5f * (vx + __shfl_xor(vx, 32));
  float oy = 0.5f * (vy + __shfl_xor(vy, 32));
  float oz = 0.5f * (vz + __shfl_xor(vz, 32));
  float ow = 0.5f * (vw + __shfl_xor(vw, 32));
  if (l < 32) {
    int jf = 4 * l;
    float4 o = make_float4(ox + b[jf], oy + b[jf + 1], oz + b[jf + 2], ow + b[jf + 3]);
    if (relu) {
      o.x = fmaxf(o.x, 0.f); o.y = fmaxf(o.y, 0.f);
      o.z = fmaxf(o.z, 0.f); o.w = fmaxf(o.w, 0.f);
    }
    ((float4*)out)[(size_t)c * 32 + l] = o;
  }
}

// ---- gated blend: out = z*xt + (1-z)*x, z = sigmoid(xt@fc1 + x@fc2 + biases)
__global__ void blend_kernel(const float* __restrict__ xt, const float* __restrict__ x,
                             const float* __restrict__ fc1W, const float* __restrict__ fc1b,
                             const float* __restrict__ fc2W, const float* __restrict__ fc2b,
                             const float* __restrict__ pb, float* __restrict__ out, int N) {
  int n0 = blockIdx.x * BROWS;
  int j = threadIdx.x;   // 0..127
  __shared__ float xtr[BROWS * C];
  __shared__ float xr[BROWS * C];
  for (int i = j; i < BROWS * C; i += C) {
    int n = n0 + i / C;
    xtr[i] = (n < N) ? xt[n0 * C + i] : 0.f;
    xr[i]  = (n < N) ? x[n0 * C + i] : 0.f;
  }
  __syncthreads();
  float s1[BROWS], s2[BROWS];
  #pragma unroll
  for (int r = 0; r < BROWS; r++) { s1[r] = 0.f; s2[r] = 0.f; }
  #pragma unroll 2
  for (int k = 0; k < C; k++) {
    float w1 = fc1W[k * C + j];
    float w2 = fc2W[k * C + j];
    #pragma unroll
    for (int r = 0; r < BROWS; r++) {
      s1[r] += xtr[r * C + k] * w1;
      s2[r] += xr[r * C + k] * w2;
    }
  }
  float bb = fc1b[j] + fc2b[j] + pb[j];
  for (int r = 0; r < BROWS; r++) {
    int n = n0 + r;
    if (n < N) {
      float t = s1[r] + s2[r] + bb;
      float z = 1.f / (1.f + __expf(-t));
      out[n * C + j] = z * xtr[r * C + j] + (1.f - z) * xr[r * C + j];
    }
  }
}

// ---- launch ----------------------------------------------------------------

extern "C" void kernel_launch(void* const* d_in, const int* in_sizes, int n_in,
                              void* d_out, int out_size, void* d_ws, size_t ws_size,
                              hipStream_t stream) {
  const float* x_in  = (const float*)d_in[0];
  const int*   ei    = (const int*)d_in[1];
  const float* ew    = (const float*)d_in[2];
  const float* gcn_W = (const float*)d_in[3];
  const float* gcn_b = (const float*)d_in[4];
  const float* g1_W  = (const float*)d_in[5];
  const float* g1_as = (const float*)d_in[6];
  const float* g1_ad = (const float*)d_in[7];
  const float* g1_b  = (const float*)d_in[8];
  const float* g2_W  = (const float*)d_in[9];
  const float* g2_as = (const float*)d_in[10];
  const float* g2_ad = (const float*)d_in[11];
  const float* g2_b  = (const float*)d_in[12];
  const float* fc1_W = (const float*)d_in[13];
  const float* fc1_b = (const float*)d_in[14];
  const float* fc2_W = (const float*)d_in[15];
  const float* fc2_b = (const float*)d_in[16];
  const float* pb    = (const float*)d_in[17];

  const int N = in_sizes[0] / F_IN;
  const int E = in_sizes[2];
  const int* row = ei;
  const int* col = ei + E;

  char* ws = (char*)d_ws;
  size_t o = 0;
  auto alloc = [&](size_t bytes) -> void* {
    void* p = ws + o;
    o += (bytes + 255) & ~(size_t)255;
    return p;
  };
  int*   cnt   = (int*)alloc((size_t)(N + 1) * 4);
  int*   cur   = (int*)alloc((size_t)N * 4);
  float* deg   = (float*)alloc((size_t)N * 4);
  size_t zero_bytes = o;                     // cnt+cur+deg at ws start
  int*   off   = (int*)alloc((size_t)(N + 1) * 4);
  float* dinv  = (float*)alloc((size_t)N * 4);
  int*   bsum  = (int*)alloc(256 * 4);
  int*   srow  = (int*)alloc((size_t)E * 4);
  float* sw    = (float*)alloc((size_t)E * 4);
  float* sarr  = (float*)alloc((size_t)N * 2 * 4);
  float* selfw = (float*)alloc((size_t)N * 2 * 4);
  float* asrc  = (float*)alloc((size_t)N * 2 * 4);
  float* adst  = (float*)alloc((size_t)N * 2 * 4);
  float* A     = (float*)alloc((size_t)N * C * 4);      // gcn xl / gat xt
  float* H     = (float*)alloc((size_t)N * C * 4);      // running x
  float* XL    = (float*)alloc((size_t)N * 2 * C * 4);  // gat xl [N,2,128]
  // alpha (2E floats = 12.8 MB) aliases d_out (N*C floats = 25.6 MB):
  // last alpha read (gat_agg2 L2) precedes the only d_out write (final blend).
  float* alpha = (float*)d_out;
  (void)ws_size; (void)n_in; (void)out_size;

  hipMemsetAsync(d_ws, 0, zero_bytes, stream);

  const int tb = 256;
  const int nP = N + 1;
  const int nb = (nP + 1023) / 1024;
  count_kernel<<<(E + tb - 1) / tb, tb, 0, stream>>>(col, ew, cnt, deg, E);
  scan1_kernel<<<nb, 256, 0, stream>>>(cnt, off, bsum, nP);
  scan2_kernel<<<1, 256, 0, stream>>>(bsum, nb);
  scan3_kernel<<<(nP + tb - 1) / tb, tb, 0, stream>>>(off, bsum, nP);
  dinv_kernel<<<(N + tb - 1) / tb, tb, 0, stream>>>(deg, dinv, N);
  scatter_kernel<<<(E + tb - 1) / tb, tb, 0, stream>>>(row, col, ew, off, dinv, cur, srow, sw, E);

  // GCN + ReLU
  gemm33_kernel<<<(N + MROWS - 1) / MROWS, C, 0, stream>>>(x_in, gcn_W, A, N);
  gcn_agg_kernel<<<(N + 3) / 4, 256, 0, stream>>>(A, off, srow, sw, dinv, gcn_b, H, N);

  // GAT layer 1 (+ReLU) + gated blend (in-place into H)
  gat_gemm_kernel<<<(N + GROWS - 1) / GROWS, 256, 0, stream>>>(H, g1_W, g1_as, g1_ad, XL, asrc, adst, N);
  att_edge_kernel<<<(N + 3) / 4, 256, 0, stream>>>(asrc, adst, off, srow, alpha, sarr, selfw, N);
  gat_agg2_kernel<<<(N + 3) / 4, 256, 0, stream>>>(XL, alpha, sarr, selfw, off, srow, g1_b, A, 1, N);
  blend_kernel<<<(N + BROWS - 1) / BROWS, C, 0, stream>>>(A, H, fc1_W, fc1_b, fc2_W, fc2_b, pb, H, N);

  // GAT layer 2 (no ReLU) + gated blend into d_out
  gat_gemm_kernel<<<(N + GROWS - 1) / GROWS, 256, 0, stream>>>(H, g2_W, g2_as, g2_ad, XL, asrc, adst, N);
  att_edge_kernel<<<(N + 3) / 4, 256, 0, stream>>>(asrc, adst, off, srow, alpha, sarr, selfw, N);
  gat_agg2_kernel<<<(N + 3) / 4, 256, 0, stream>>>(XL, alpha, sarr, selfw, off, srow, g2_b, A, 0, N);
  blend_kernel<<<(N + BROWS - 1) / BROWS, C, 0, stream>>>(A, H, fc1_W, fc1_b, fc2_W, fc2_b, pb, (float*)d_out, N);
}

// Round 3
// 1520.693 us; speedup vs baseline: 1.1782x; 1.0293x over previous
//
#include <hip/hip_runtime.h>

#define F_IN 33
#define C 128      // F_OUT
#define GROWS 16   // rows per block in gat_gemm
#define BROWS 16   // rows per block in blend
#define MROWS 16   // rows per block in gemm33

__device__ __forceinline__ unsigned short f2bf(float f) {
  unsigned u = __float_as_uint(f);
  unsigned r = (u + 0x7fff + ((u >> 16) & 1)) >> 16;   // RNE
  return (unsigned short)r;
}

// ---- CSR build -------------------------------------------------------------

__global__ void count_kernel(const int* __restrict__ col, const float* __restrict__ w,
                             int* __restrict__ cnt, float* __restrict__ deg, int E) {
  int e = blockIdx.x * blockDim.x + threadIdx.x;
  if (e < E) {
    int c = col[e];
    atomicAdd(&cnt[c], 1);
    atomicAdd(&deg[c], w[e]);
  }
}

__global__ void scan1_kernel(const int* __restrict__ cnt, int* __restrict__ out,
                             int* __restrict__ bsum, int n) {
  __shared__ int lds[256];
  int t = threadIdx.x;
  int base = blockIdx.x * 1024 + t * 4;
  int v0 = (base + 0 < n) ? cnt[base + 0] : 0;
  int v1 = (base + 1 < n) ? cnt[base + 1] : 0;
  int v2 = (base + 2 < n) ? cnt[base + 2] : 0;
  int v3 = (base + 3 < n) ? cnt[base + 3] : 0;
  int tot = v0 + v1 + v2 + v3;
  lds[t] = tot;
  __syncthreads();
  for (int o = 1; o < 256; o <<= 1) {
    int x = (t >= o) ? lds[t - o] : 0;
    __syncthreads();
    lds[t] += x;
    __syncthreads();
  }
  int excl = lds[t] - tot;
  if (t == 255) bsum[blockIdx.x] = lds[255];
  if (base + 0 < n) out[base + 0] = excl;
  if (base + 1 < n) out[base + 1] = excl + v0;
  if (base + 2 < n) out[base + 2] = excl + v0 + v1;
  if (base + 3 < n) out[base + 3] = excl + v0 + v1 + v2;
}

__global__ void scan2_kernel(int* __restrict__ bsum, int nb) {
  __shared__ int lds[256];
  int t = threadIdx.x;
  int v = (t < nb) ? bsum[t] : 0;
  lds[t] = v;
  __syncthreads();
  for (int o = 1; o < 256; o <<= 1) {
    int x = (t >= o) ? lds[t - o] : 0;
    __syncthreads();
    lds[t] += x;
    __syncthreads();
  }
  if (t < nb) bsum[t] = lds[t] - v;
}

__global__ void scan3_kernel(int* __restrict__ off, const int* __restrict__ bsum, int n) {
  int i = blockIdx.x * blockDim.x + threadIdx.x;
  if (i < n) off[i] += bsum[i >> 10];
}

__global__ void dinv_kernel(const float* __restrict__ deg, float* __restrict__ dinv, int N) {
  int i = blockIdx.x * blockDim.x + threadIdx.x;
  if (i < N) dinv[i] = rsqrtf(deg[i] + 1.0f);
}

// one int2 {row, dinv[row]*w} per edge: single 8B random store
__global__ void scatter_kernel(const int* __restrict__ row, const int* __restrict__ col,
                               const float* __restrict__ w, const int* __restrict__ off,
                               const float* __restrict__ dinv, int* __restrict__ cur,
                               int2* __restrict__ sedge, int E) {
  int e = blockIdx.x * blockDim.x + threadIdx.x;
  if (e < E) {
    int c = col[e];
    int r = row[e];
    int p = off[c] + atomicAdd(&cur[c], 1);
    sedge[p] = make_int2(r, __float_as_int(dinv[r] * w[e]));
  }
}

// ---- GCN -------------------------------------------------------------------

__global__ void gemm33_kernel(const float* __restrict__ x, const float* __restrict__ W,
                              float* __restrict__ out, int N) {
  int n0 = blockIdx.x * MROWS;
  int t = threadIdx.x;   // 0..127
  __shared__ float xr[MROWS * F_IN];
  for (int i = t; i < MROWS * F_IN; i += 128) {
    int idx = n0 * F_IN + i;
    xr[i] = (idx < N * F_IN) ? x[idx] : 0.f;
  }
  __syncthreads();
  float acc[MROWS];
  #pragma unroll
  for (int r = 0; r < MROWS; r++) acc[r] = 0.f;
  #pragma unroll
  for (int k = 0; k < F_IN; k++) {
    float wv = W[k * C + t];
    #pragma unroll
    for (int r = 0; r < MROWS; r++) acc[r] += xr[r * F_IN + k] * wv;
  }
  for (int r = 0; r < MROWS; r++) {
    int n = n0 + r;
    if (n < N) out[n * C + t] = acc[r];
  }
}

// 4 nodes/block, one wave each, float2 per lane
__global__ void gcn_agg_kernel(const float* __restrict__ xl, const int* __restrict__ off,
                               const int2* __restrict__ sedge, const float* __restrict__ dinv,
                               const float* __restrict__ b, float* __restrict__ out, int N) {
  int c = blockIdx.x * 4 + (threadIdx.x >> 6);
  if (c >= N) return;
  int l = threadIdx.x & 63;
  const float2* xv = (const float2*)xl;
  float dc = dinv[c];
  float2 xc = xv[(size_t)c * 64 + l];
  float a0x = dc * xc.x, a0y = dc * xc.y;
  float a1x = 0.f, a1y = 0.f;
  int p = off[c], p1 = off[c + 1];
  for (; p + 2 <= p1; p += 2) {
    int2 e0 = sedge[p], e1 = sedge[p + 1];
    float w0 = __int_as_float(e0.y), w1 = __int_as_float(e1.y);
    float2 v0 = xv[(size_t)e0.x * 64 + l];
    float2 v1 = xv[(size_t)e1.x * 64 + l];
    a0x += w0 * v0.x; a0y += w0 * v0.y;
    a1x += w1 * v1.x; a1y += w1 * v1.y;
  }
  if (p < p1) {
    int2 e0 = sedge[p];
    float w0 = __int_as_float(e0.y);
    float2 v0 = xv[(size_t)e0.x * 64 + l];
    a0x += w0 * v0.x; a0y += w0 * v0.y;
  }
  float2 bb = ((const float2*)b)[l];
  float2 o;
  o.x = fmaxf(dc * (a0x + a1x) + bb.x, 0.f);
  o.y = fmaxf(dc * (a0y + a1y) + bb.y, 0.f);
  ((float2*)out)[(size_t)c * 64 + l] = o;
}

// ---- GAT -------------------------------------------------------------------

// x [N,128] @ W [128,256] -> XLb [N,256] bf16, fused attention dots.
// 128 threads; thread j computes output cols j (head0) and j+128 (head1).
__global__ void gat_gemm_kernel(const float* __restrict__ x, const float* __restrict__ W,
                                const float* __restrict__ as, const float* __restrict__ ad,
                                unsigned short* __restrict__ XLb, float* __restrict__ asrc,
                                float* __restrict__ adst, int N) {
  int n0 = blockIdx.x * GROWS;
  int j = threadIdx.x;   // 0..127
  __shared__ float xr[GROWS * C];          // 8 KB
  __shared__ float xls[GROWS * 264];       // 16.5 KB
  {
    float4* xr4 = (float4*)xr;
    const float4* x4 = (const float4*)x;
    int tot4 = GROWS * C / 4;              // 512
    for (int i = j; i < tot4; i += 128) {
      int n = n0 + (i * 4) / C;
      xr4[i] = (n < N) ? x4[n0 * (C / 4) + i] : make_float4(0.f, 0.f, 0.f, 0.f);
    }
  }
  __syncthreads();
  float acc0[GROWS], acc1[GROWS];
  #pragma unroll
  for (int r = 0; r < GROWS; r++) { acc0[r] = 0.f; acc1[r] = 0.f; }
  #pragma unroll 2
  for (int k4 = 0; k4 < C; k4 += 4) {
    float wa0 = W[(k4 + 0) * 2 * C + j],       wb0 = W[(k4 + 0) * 2 * C + j + C];
    float wa1 = W[(k4 + 1) * 2 * C + j],       wb1 = W[(k4 + 1) * 2 * C + j + C];
    float wa2 = W[(k4 + 2) * 2 * C + j],       wb2 = W[(k4 + 2) * 2 * C + j + C];
    float wa3 = W[(k4 + 3) * 2 * C + j],       wb3 = W[(k4 + 3) * 2 * C + j + C];
    #pragma unroll
    for (int r = 0; r < GROWS; r++) {
      float4 xv = *(const float4*)&xr[r * C + k4];
      acc0[r] += xv.x * wa0 + xv.y * wa1 + xv.z * wa2 + xv.w * wa3;
      acc1[r] += xv.x * wb0 + xv.y * wb1 + xv.z * wb2 + xv.w * wb3;
    }
  }
  #pragma unroll
  for (int r = 0; r < GROWS; r++) {
    int n = n0 + r;
    xls[r * 264 + j] = acc0[r];
    xls[r * 264 + C + j] = acc1[r];
    if (n < N) {
      XLb[(size_t)n * 2 * C + j]     = f2bf(acc0[r]);
      XLb[(size_t)n * 2 * C + C + j] = f2bf(acc1[r]);
    }
  }
  __syncthreads();
  // dots: 16 teams (one per row) x 8 threads; both heads per team
  int r = j >> 3, sub = j & 7;
  float sa0 = 0.f, sd0 = 0.f, sa1 = 0.f, sd1 = 0.f;
  for (int k = sub; k < C; k += 8) {
    float v0 = xls[r * 264 + k];
    float v1 = xls[r * 264 + C + k];
    sa0 += v0 * as[k];      sd0 += v0 * ad[k];
    sa1 += v1 * as[C + k];  sd1 += v1 * ad[C + k];
  }
  #pragma unroll
  for (int o = 4; o > 0; o >>= 1) {
    sa0 += __shfl_down(sa0, o); sd0 += __shfl_down(sd0, o);
    sa1 += __shfl_down(sa1, o); sd1 += __shfl_down(sd1, o);
  }
  int n = n0 + r;
  if (sub == 0 && n < N) {
    asrc[n * 2 + 0] = sa0; adst[n * 2 + 0] = sd0;
    asrc[n * 2 + 1] = sa1; adst[n * 2 + 1] = sd1;
  }
}

// edge softmax phase 1: per-node max, alpha=exp(e-m), denom, self weight.
__global__ void att_edge_kernel(const float* __restrict__ asrc, const float* __restrict__ adst,
                                const int* __restrict__ off, const int2* __restrict__ sedge,
                                float* __restrict__ alpha, float* __restrict__ sarr,
                                float* __restrict__ selfw, int N) {
  int c = blockIdx.x * 4 + (threadIdx.x >> 6);
  if (c >= N) return;
  int lane = threadIdx.x & 63;
  float ad0 = adst[c * 2 + 0], ad1 = adst[c * 2 + 1];
  int p0 = off[c], p1 = off[c + 1];
  float e00 = asrc[c * 2 + 0] + ad0; e00 = e00 > 0.f ? e00 : 0.2f * e00;
  float e01 = asrc[c * 2 + 1] + ad1; e01 = e01 > 0.f ? e01 : 0.2f * e01;
  float m0 = e00, m1 = e01;
  for (int p = p0 + lane; p < p1; p += 64) {
    int r = sedge[p].x;
    float e0 = asrc[r * 2 + 0] + ad0; e0 = e0 > 0.f ? e0 : 0.2f * e0;
    float e1 = asrc[r * 2 + 1] + ad1; e1 = e1 > 0.f ? e1 : 0.2f * e1;
    m0 = fmaxf(m0, e0); m1 = fmaxf(m1, e1);
  }
  #pragma unroll
  for (int o = 32; o > 0; o >>= 1) {
    m0 = fmaxf(m0, __shfl_xor(m0, o));
    m1 = fmaxf(m1, __shfl_xor(m1, o));
  }
  float s0 = 0.f, s1 = 0.f;
  for (int p = p0 + lane; p < p1; p += 64) {
    int r = sedge[p].x;
    float e0 = asrc[r * 2 + 0] + ad0; e0 = e0 > 0.f ? e0 : 0.2f * e0;
    float e1 = asrc[r * 2 + 1] + ad1; e1 = e1 > 0.f ? e1 : 0.2f * e1;
    float a0 = __expf(e0 - m0), a1 = __expf(e1 - m1);
    ((float2*)alpha)[p] = make_float2(a0, a1);
    s0 += a0; s1 += a1;
  }
  #pragma unroll
  for (int o = 32; o > 0; o >>= 1) {
    s0 += __shfl_xor(s0, o);
    s1 += __shfl_xor(s1, o);
  }
  float w0 = __expf(e00 - m0), w1 = __expf(e01 - m1);
  if (lane == 0) {
    sarr[c * 2 + 0] = s0 + w0;
    sarr[c * 2 + 1] = s1 + w1;
    selfw[c * 2 + 0] = w0;
    selfw[c * 2 + 1] = w1;
  }
}

// aggregate: bf16 gather. 4 nodes/block, 1 wave each; lane l covers
// elements 4l..4l+3 of the 256-bf16 row (8B/lane); shfl head-mean.
__global__ void gat_agg2_kernel(const unsigned short* __restrict__ XLb,
                                const float* __restrict__ alpha,
                                const float* __restrict__ sarr, const float* __restrict__ selfw,
                                const int* __restrict__ off, const int2* __restrict__ sedge,
                                const float* __restrict__ b, float* __restrict__ out,
                                int relu, int N) {
  int c = blockIdx.x * 4 + (threadIdx.x >> 6);
  if (c >= N) return;
  int l = threadIdx.x & 63;
  int h = l >> 5;
  const uint2* xv = (const uint2*)XLb;   // row = 64 uint2 (512B)
  uint2 uc = xv[(size_t)c * 64 + l];
  float swt = selfw[c * 2 + h];
  float c0 = __uint_as_float(uc.x << 16);
  float c1 = __uint_as_float(uc.x & 0xffff0000u);
  float c2 = __uint_as_float(uc.y << 16);
  float c3 = __uint_as_float(uc.y & 0xffff0000u);
  float a0x = swt * c0, a0y = swt * c1, a0z = swt * c2, a0w = swt * c3;
  float a1x = 0.f, a1y = 0.f, a1z = 0.f, a1w = 0.f;
  int p = off[c], p1 = off[c + 1];
  for (; p + 2 <= p1; p += 2) {
    int r0 = sedge[p].x, r1 = sedge[p + 1].x;
    float al0 = alpha[p * 2 + h], al1 = alpha[(p + 1) * 2 + h];
    uint2 u0 = xv[(size_t)r0 * 64 + l];
    uint2 u1 = xv[(size_t)r1 * 64 + l];
    a0x += al0 * __uint_as_float(u0.x << 16);
    a0y += al0 * __uint_as_float(u0.x & 0xffff0000u);
    a0z += al0 * __uint_as_float(u0.y << 16);
    a0w += al0 * __uint_as_float(u0.y & 0xffff0000u);
    a1x += al1 * __uint_as_float(u1.x << 16);
    a1y += al1 * __uint_as_float(u1.x & 0xffff0000u);
    a1z += al1 * __uint_as_float(u1.y << 16);
    a1w += al1 * __uint_as_float(u1.y & 0xffff0000u);
  }
  if (p < p1) {
    float al = alpha[p * 2 + h];
    uint2 u0 = xv[(size_t)sedge[p].x * 64 + l];
    a0x += al * __uint_as_float(u0.x << 16);
    a0y += al * __uint_as_float(u0.x & 0xffff0000u);
    a0z += al * __uint_as_float(u0.y << 16);
    a0w += al * __uint_as_float(u0.y & 0xffff0000u);
  }
  float inv_s = 1.f / sarr[c * 2 + h];
  float vx = (a0x + a1x) * inv_s, vy = (a0y + a1y) * inv_s;
  float vz = (a0z + a1z) * inv_s, vw = (a0w + a1w) * inv_s;
  float ox = 0.5f * (vx + __shfl_xor(vx, 32));
  float oy = 0.5f * (vy + __shfl_xor(vy, 32));
  float oz = 0.5f * (vz + __shfl_xor(vz, 32));
  float ow = 0.5f * (vw + __shfl_xor(vw, 32));
  if (l < 32) {
    float4 bb = ((const float4*)b)[l];
    float4 o = make_float4(ox + bb.x, oy + bb.y, oz + bb.z, ow + bb.w);
    if (relu) {
      o.x = fmaxf(o.x, 0.f); o.y = fmaxf(o.y, 0.f);
      o.z = fmaxf(o.z, 0.f); o.w = fmaxf(o.w, 0.f);
    }
    ((float4*)out)[(size_t)c * 32 + l] = o;
  }
}

// ---- gated blend -----------------------------------------------------------
__global__ void blend_kernel(const float* __restrict__ xt, const float* __restrict__ x,
                             const float* __restrict__ fc1W, const float* __restrict__ fc1b,
                             const float* __restrict__ fc2W, const float* __restrict__ fc2b,
                             const float* __restrict__ pb, float* __restrict__ out, int N) {
  int n0 = blockIdx.x * BROWS;
  int j = threadIdx.x;   // 0..127
  __shared__ float xtr[BROWS * C];
  __shared__ float xr[BROWS * C];
  {
    float4* a4 = (float4*)xtr;
    float4* b4 = (float4*)xr;
    const float4* xt4 = (const float4*)xt;
    const float4* x4 = (const float4*)x;
    int tot4 = BROWS * C / 4;    // 512
    for (int i = j; i < tot4; i += 128) {
      int n = n0 + (i * 4) / C;
      if (n < N) {
        a4[i] = xt4[n0 * (C / 4) + i];
        b4[i] = x4[n0 * (C / 4) + i];
      } else {
        a4[i] = make_float4(0.f, 0.f, 0.f, 0.f);
        b4[i] = make_float4(0.f, 0.f, 0.f, 0.f);
      }
    }
  }
  __syncthreads();
  float s1[BROWS], s2[BROWS];
  #pragma unroll
  for (int r = 0; r < BROWS; r++) { s1[r] = 0.f; s2[r] = 0.f; }
  #pragma unroll 2
  for (int k4 = 0; k4 < C; k4 += 4) {
    float w1a = fc1W[(k4 + 0) * C + j], w2a = fc2W[(k4 + 0) * C + j];
    float w1b = fc1W[(k4 + 1) * C + j], w2b = fc2W[(k4 + 1) * C + j];
    float w1c = fc1W[(k4 + 2) * C + j], w2c = fc2W[(k4 + 2) * C + j];
    float w1d = fc1W[(k4 + 3) * C + j], w2d = fc2W[(k4 + 3) * C + j];
    #pragma unroll
    for (int r = 0; r < BROWS; r++) {
      float4 t4 = *(const float4*)&xtr[r * C + k4];
      float4 x4 = *(const float4*)&xr[r * C + k4];
      s1[r] += t4.x * w1a + t4.y * w1b + t4.z * w1c + t4.w * w1d;
      s2[r] += x4.x * w2a + x4.y * w2b + x4.z * w2c + x4.w * w2d;
    }
  }
  float bb = fc1b[j] + fc2b[j] + pb[j];
  for (int r = 0; r < BROWS; r++) {
    int n = n0 + r;
    if (n < N) {
      float t = s1[r] + s2[r] + bb;
      float z = 1.f / (1.f + __expf(-t));
      out[n * C + j] = z * xtr[r * C + j] + (1.f - z) * xr[r * C + j];
    }
  }
}

// ---- launch ----------------------------------------------------------------

extern "C" void kernel_launch(void* const* d_in, const int* in_sizes, int n_in,
                              void* d_out, int out_size, void* d_ws, size_t ws_size,
                              hipStream_t stream) {
  const float* x_in  = (const float*)d_in[0];
  const int*   ei    = (const int*)d_in[1];
  const float* ew    = (const float*)d_in[2];
  const float* gcn_W = (const float*)d_in[3];
  const float* gcn_b = (const float*)d_in[4];
  const float* g1_W  = (const float*)d_in[5];
  const float* g1_as = (const float*)d_in[6];
  const float* g1_ad = (const float*)d_in[7];
  const float* g1_b  = (const float*)d_in[8];
  const float* g2_W  = (const float*)d_in[9];
  const float* g2_as = (const float*)d_in[10];
  const float* g2_ad = (const float*)d_in[11];
  const float* g2_b  = (const float*)d_in[12];
  const float* fc1_W = (const float*)d_in[13];
  const float* fc1_b = (const float*)d_in[14];
  const float* fc2_W = (const float*)d_in[15];
  const float* fc2_b = (const float*)d_in[16];
  const float* pb    = (const float*)d_in[17];

  const int N = in_sizes[0] / F_IN;
  const int E = in_sizes[2];
  const int* row = ei;
  const int* col = ei + E;

  char* ws = (char*)d_ws;
  size_t o = 0;
  auto alloc = [&](size_t bytes) -> void* {
    void* p = ws + o;
    o += (bytes + 255) & ~(size_t)255;
    return p;
  };
  int*   cnt   = (int*)alloc((size_t)(N + 1) * 4);
  int*   cur   = (int*)alloc((size_t)N * 4);
  float* deg   = (float*)alloc((size_t)N * 4);
  size_t zero_bytes = o;                     // cnt+cur+deg at ws start
  int*   off   = (int*)alloc((size_t)(N + 1) * 4);
  float* dinv  = (float*)alloc((size_t)N * 4);
  int*   bsum  = (int*)alloc(256 * 4);
  int2*  sedge = (int2*)alloc((size_t)E * 8);
  float* sarr  = (float*)alloc((size_t)N * 2 * 4);
  float* selfw = (float*)alloc((size_t)N * 2 * 4);
  float* asrc  = (float*)alloc((size_t)N * 2 * 4);
  float* adst  = (float*)alloc((size_t)N * 2 * 4);
  float* A     = (float*)alloc((size_t)N * C * 4);            // gcn xl / gat xt
  float* H     = (float*)alloc((size_t)N * C * 4);            // running x
  unsigned short* XLb = (unsigned short*)alloc((size_t)N * 2 * C * 2);  // bf16 [N,256]
  // alpha (2E floats = 12.8 MB) aliases d_out (25.6 MB): last alpha read
  // (gat_agg2) precedes the only d_out write (final blend).
  float* alpha = (float*)d_out;
  (void)ws_size; (void)n_in; (void)out_size;

  hipMemsetAsync(d_ws, 0, zero_bytes, stream);

  const int tb = 256;
  const int nP = N + 1;
  const int nb = (nP + 1023) / 1024;
  count_kernel<<<(E + tb - 1) / tb, tb, 0, stream>>>(col, ew, cnt, deg, E);
  scan1_kernel<<<nb, 256, 0, stream>>>(cnt, off, bsum, nP);
  scan2_kernel<<<1, 256, 0, stream>>>(bsum, nb);
  scan3_kernel<<<(nP + tb - 1) / tb, tb, 0, stream>>>(off, bsum, nP);
  dinv_kernel<<<(N + tb - 1) / tb, tb, 0, stream>>>(deg, dinv, N);
  scatter_kernel<<<(E + tb - 1) / tb, tb, 0, stream>>>(row, col, ew, off, dinv, cur, sedge, E);

  // GCN + ReLU
  gemm33_kernel<<<(N + MROWS - 1) / MROWS, C, 0, stream>>>(x_in, gcn_W, A, N);
  gcn_agg_kernel<<<(N + 3) / 4, 256, 0, stream>>>(A, off, sedge, dinv, gcn_b, H, N);

  // GAT layer 1 (+ReLU) + gated blend (in-place into H)
  gat_gemm_kernel<<<(N + GROWS - 1) / GROWS, C, 0, stream>>>(H, g1_W, g1_as, g1_ad, XLb, asrc, adst, N);
  att_edge_kernel<<<(N + 3) / 4, 256, 0, stream>>>(asrc, adst, off, sedge, alpha, sarr, selfw, N);
  gat_agg2_kernel<<<(N + 3) / 4, 256, 0, stream>>>(XLb, alpha, sarr, selfw, off, sedge, g1_b, A, 1, N);
  blend_kernel<<<(N + BROWS - 1) / BROWS, C, 0, stream>>>(A, H, fc1_W, fc1_b, fc2_W, fc2_b, pb, H, N);

  // GAT layer 2 (no ReLU) + gated blend into d_out
  gat_gemm_kernel<<<(N + GROWS - 1) / GROWS, C, 0, stream>>>(H, g2_W, g2_as, g2_ad, XLb, asrc, adst, N);
  att_edge_kernel<<<(N + 3) / 4, 256, 0, stream>>>(asrc, adst, off, sedge, alpha, sarr, selfw, N);
  gat_agg2_kernel<<<(N + 3) / 4, 256, 0, stream>>>(XLb, alpha, sarr, selfw, off, sedge, g2_b, A, 0, N);
  blend_kernel<<<(N + BROWS - 1) / BROWS, C, 0, stream>>>(A, H, fc1_W, fc1_b, fc2_W, fc2_b, pb, (float*)d_out, N);
}

// Round 4
// 1260.699 us; speedup vs baseline: 1.4212x; 1.2062x over previous
//
#include <hip/hip_runtime.h>

#define F_IN 33
#define C 128      // F_OUT
#define GROWS 16   // rows per block in gat_gemm
#define BROWS 16   // rows per block in blend
#define MROWS 8    // rows per block in gemm33
#define MAXDEG 128 // LDS-staged alpha cap per node

__device__ __forceinline__ unsigned short f2bf(float f) {
  unsigned u = __float_as_uint(f);
  unsigned r = (u + 0x7fff + ((u >> 16) & 1)) >> 16;   // RNE
  return (unsigned short)r;
}
__device__ __forceinline__ float bflo(unsigned u) { return __uint_as_float(u << 16); }
__device__ __forceinline__ float bfhi(unsigned u) { return __uint_as_float(u & 0xffff0000u); }

// ---- CSR build -------------------------------------------------------------

__global__ void count_kernel(const int* __restrict__ col, const float* __restrict__ w,
                             int* __restrict__ cnt, float* __restrict__ deg, int E) {
  int e = blockIdx.x * blockDim.x + threadIdx.x;
  if (e < E) {
    int c = col[e];
    atomicAdd(&cnt[c], 1);
    atomicAdd(&deg[c], w[e]);
  }
}

__global__ void scan1_kernel(const int* __restrict__ cnt, int* __restrict__ out,
                             int* __restrict__ bsum, int n) {
  __shared__ int lds[256];
  int t = threadIdx.x;
  int base = blockIdx.x * 1024 + t * 4;
  int v0 = (base + 0 < n) ? cnt[base + 0] : 0;
  int v1 = (base + 1 < n) ? cnt[base + 1] : 0;
  int v2 = (base + 2 < n) ? cnt[base + 2] : 0;
  int v3 = (base + 3 < n) ? cnt[base + 3] : 0;
  int tot = v0 + v1 + v2 + v3;
  lds[t] = tot;
  __syncthreads();
  for (int o = 1; o < 256; o <<= 1) {
    int x = (t >= o) ? lds[t - o] : 0;
    __syncthreads();
    lds[t] += x;
    __syncthreads();
  }
  int excl = lds[t] - tot;
  if (t == 255) bsum[blockIdx.x] = lds[255];
  if (base + 0 < n) out[base + 0] = excl;
  if (base + 1 < n) out[base + 1] = excl + v0;
  if (base + 2 < n) out[base + 2] = excl + v0 + v1;
  if (base + 3 < n) out[base + 3] = excl + v0 + v1 + v2;
}

__global__ void scan2_kernel(int* __restrict__ bsum, int nb) {
  __shared__ int lds[256];
  int t = threadIdx.x;
  int v = (t < nb) ? bsum[t] : 0;
  lds[t] = v;
  __syncthreads();
  for (int o = 1; o < 256; o <<= 1) {
    int x = (t >= o) ? lds[t - o] : 0;
    __syncthreads();
    lds[t] += x;
    __syncthreads();
  }
  if (t < nb) bsum[t] = lds[t] - v;
}

// scan3 + dinv fused (independent index ranges)
__global__ void scan3_dinv_kernel(int* __restrict__ off, const int* __restrict__ bsum,
                                  const float* __restrict__ deg, float* __restrict__ dinv,
                                  int n, int N) {
  int i = blockIdx.x * blockDim.x + threadIdx.x;
  if (i < n) off[i] += bsum[i >> 10];
  if (i < N) dinv[i] = rsqrtf(deg[i] + 1.0f);
}

// one int2 {row, dinv[row]*w} per edge
__global__ void scatter_kernel(const int* __restrict__ row, const int* __restrict__ col,
                               const float* __restrict__ w, const int* __restrict__ off,
                               const float* __restrict__ dinv, int* __restrict__ cur,
                               int2* __restrict__ sedge, int E) {
  int e = blockIdx.x * blockDim.x + threadIdx.x;
  if (e < E) {
    int c = col[e];
    int r = row[e];
    int p = off[c] + atomicAdd(&cur[c], 1);
    sedge[p] = make_int2(r, __float_as_int(dinv[r] * w[e]));
  }
}

// ---- GCN -------------------------------------------------------------------

// x [N,33] @ W [33,128] -> bf16 out [N,128]
__global__ void gemm33_kernel(const float* __restrict__ x, const float* __restrict__ W,
                              unsigned short* __restrict__ out, int N) {
  int n0 = blockIdx.x * MROWS;
  int t = threadIdx.x;   // 0..127
  __shared__ float xr[MROWS * F_IN];
  for (int i = t; i < MROWS * F_IN; i += 128) {
    int idx = n0 * F_IN + i;
    xr[i] = (idx < N * F_IN) ? x[idx] : 0.f;
  }
  __syncthreads();
  float acc[MROWS];
  #pragma unroll
  for (int r = 0; r < MROWS; r++) acc[r] = 0.f;
  #pragma unroll
  for (int k = 0; k < F_IN; k++) {
    float wv = W[k * C + t];
    #pragma unroll
    for (int r = 0; r < MROWS; r++) acc[r] += xr[r * F_IN + k] * wv;
  }
  for (int r = 0; r < MROWS; r++) {
    int n = n0 + r;
    if (n < N) out[n * C + t] = f2bf(acc[r]);
  }
}

// 4 nodes/block, one wave each; bf16 gather (256B/edge), 4-deep unroll
__global__ void gcn_agg_kernel(const unsigned short* __restrict__ Ab, const int* __restrict__ off,
                               const int2* __restrict__ sedge, const float* __restrict__ dinv,
                               const float* __restrict__ b, float* __restrict__ out, int N) {
  int c = blockIdx.x * 4 + (threadIdx.x >> 6);
  if (c >= N) return;
  int l = threadIdx.x & 63;
  const unsigned* xv = (const unsigned*)Ab;   // row = 64 dwords (256B)
  float dc = dinv[c];
  unsigned uc = xv[(size_t)c * 64 + l];
  float A0x = dc * bflo(uc), A0y = dc * bfhi(uc);
  float A1x = 0.f, A1y = 0.f, A2x = 0.f, A2y = 0.f, A3x = 0.f, A3y = 0.f;
  int p = off[c], p1 = off[c + 1];
  for (; p + 4 <= p1; p += 4) {
    int2 e0 = sedge[p], e1 = sedge[p + 1], e2 = sedge[p + 2], e3 = sedge[p + 3];
    unsigned u0 = xv[(size_t)e0.x * 64 + l];
    unsigned u1 = xv[(size_t)e1.x * 64 + l];
    unsigned u2 = xv[(size_t)e2.x * 64 + l];
    unsigned u3 = xv[(size_t)e3.x * 64 + l];
    float w0 = __int_as_float(e0.y), w1 = __int_as_float(e1.y);
    float w2 = __int_as_float(e2.y), w3 = __int_as_float(e3.y);
    A0x += w0 * bflo(u0); A0y += w0 * bfhi(u0);
    A1x += w1 * bflo(u1); A1y += w1 * bfhi(u1);
    A2x += w2 * bflo(u2); A2y += w2 * bfhi(u2);
    A3x += w3 * bflo(u3); A3y += w3 * bfhi(u3);
  }
  for (; p < p1; p++) {
    int2 e0 = sedge[p];
    unsigned u0 = xv[(size_t)e0.x * 64 + l];
    float w0 = __int_as_float(e0.y);
    A0x += w0 * bflo(u0); A0y += w0 * bfhi(u0);
  }
  float2 bb = ((const float2*)b)[l];
  float2 o;
  o.x = fmaxf(dc * (A0x + A1x + A2x + A3x) + bb.x, 0.f);
  o.y = fmaxf(dc * (A0y + A1y + A2y + A3y) + bb.y, 0.f);
  ((float2*)out)[(size_t)c * 64 + l] = o;
}

// ---- GAT -------------------------------------------------------------------

// x [N,128] @ W [128,256] -> XLb [N,256] bf16, fused attention dots.
__global__ void gat_gemm_kernel(const float* __restrict__ x, const float* __restrict__ W,
                                const float* __restrict__ as, const float* __restrict__ ad,
                                unsigned short* __restrict__ XLb, float* __restrict__ asrc,
                                float* __restrict__ adst, int N) {
  int n0 = blockIdx.x * GROWS;
  int j = threadIdx.x;   // 0..127
  __shared__ float xr[GROWS * C];          // 8 KB
  __shared__ float xls[GROWS * 264];       // 16.5 KB
  {
    float4* xr4 = (float4*)xr;
    const float4* x4 = (const float4*)x;
    int tot4 = GROWS * C / 4;              // 512
    for (int i = j; i < tot4; i += 128) {
      int n = n0 + (i * 4) / C;
      xr4[i] = (n < N) ? x4[n0 * (C / 4) + i] : make_float4(0.f, 0.f, 0.f, 0.f);
    }
  }
  __syncthreads();
  float acc0[GROWS], acc1[GROWS];
  #pragma unroll
  for (int r = 0; r < GROWS; r++) { acc0[r] = 0.f; acc1[r] = 0.f; }
  #pragma unroll 2
  for (int k4 = 0; k4 < C; k4 += 4) {
    float wa0 = W[(k4 + 0) * 2 * C + j],       wb0 = W[(k4 + 0) * 2 * C + j + C];
    float wa1 = W[(k4 + 1) * 2 * C + j],       wb1 = W[(k4 + 1) * 2 * C + j + C];
    float wa2 = W[(k4 + 2) * 2 * C + j],       wb2 = W[(k4 + 2) * 2 * C + j + C];
    float wa3 = W[(k4 + 3) * 2 * C + j],       wb3 = W[(k4 + 3) * 2 * C + j + C];
    #pragma unroll
    for (int r = 0; r < GROWS; r++) {
      float4 xv = *(const float4*)&xr[r * C + k4];
      acc0[r] += xv.x * wa0 + xv.y * wa1 + xv.z * wa2 + xv.w * wa3;
      acc1[r] += xv.x * wb0 + xv.y * wb1 + xv.z * wb2 + xv.w * wb3;
    }
  }
  #pragma unroll
  for (int r = 0; r < GROWS; r++) {
    int n = n0 + r;
    xls[r * 264 + j] = acc0[r];
    xls[r * 264 + C + j] = acc1[r];
    if (n < N) {
      XLb[(size_t)n * 2 * C + j]     = f2bf(acc0[r]);
      XLb[(size_t)n * 2 * C + C + j] = f2bf(acc1[r]);
    }
  }
  __syncthreads();
  int r = j >> 3, sub = j & 7;
  float sa0 = 0.f, sd0 = 0.f, sa1 = 0.f, sd1 = 0.f;
  for (int k = sub; k < C; k += 8) {
    float v0 = xls[r * 264 + k];
    float v1 = xls[r * 264 + C + k];
    sa0 += v0 * as[k];      sd0 += v0 * ad[k];
    sa1 += v1 * as[C + k];  sd1 += v1 * ad[C + k];
  }
  #pragma unroll
  for (int o = 4; o > 0; o >>= 1) {
    sa0 += __shfl_down(sa0, o); sd0 += __shfl_down(sd0, o);
    sa1 += __shfl_down(sa1, o); sd1 += __shfl_down(sd1, o);
  }
  int n = n0 + r;
  if (sub == 0 && n < N) {
    asrc[n * 2 + 0] = sa0; adst[n * 2 + 0] = sd0;
    asrc[n * 2 + 1] = sa1; adst[n * 2 + 1] = sd1;
  }
}

// fused edge-softmax + aggregate + head-mean. 4 nodes/block, 1 wave/node.
// alpha staged in LDS (deg<=MAXDEG fast path; rare recompute tail otherwise).
__global__ void gat_fused_kernel(const unsigned short* __restrict__ XLb,
                                 const float* __restrict__ asrc, const float* __restrict__ adst,
                                 const int* __restrict__ off, const int2* __restrict__ sedge,
                                 const float* __restrict__ b, float* __restrict__ out,
                                 int relu, int N) {
  __shared__ float lalpha[4][MAXDEG][2];   // 4 KB
  int slot = threadIdx.x >> 6;
  int c = blockIdx.x * 4 + slot;
  if (c >= N) return;                      // no __syncthreads below: wave-local only
  int l = threadIdx.x & 63;
  float ad0 = adst[c * 2 + 0], ad1 = adst[c * 2 + 1];
  int p0 = off[c], p1 = off[c + 1];
  // self-loop scores
  float e00 = asrc[c * 2 + 0] + ad0; e00 = e00 > 0.f ? e00 : 0.2f * e00;
  float e01 = asrc[c * 2 + 1] + ad1; e01 = e01 > 0.f ? e01 : 0.2f * e01;
  float m0 = e00, m1 = e01;
  for (int p = p0 + l; p < p1; p += 64) {
    int r = sedge[p].x;
    float e0 = asrc[r * 2 + 0] + ad0; e0 = e0 > 0.f ? e0 : 0.2f * e0;
    float e1 = asrc[r * 2 + 1] + ad1; e1 = e1 > 0.f ? e1 : 0.2f * e1;
    m0 = fmaxf(m0, e0); m1 = fmaxf(m1, e1);
  }
  #pragma unroll
  for (int o = 32; o > 0; o >>= 1) {
    m0 = fmaxf(m0, __shfl_xor(m0, o));
    m1 = fmaxf(m1, __shfl_xor(m1, o));
  }
  float s0 = 0.f, s1 = 0.f;
  for (int p = p0 + l; p < p1; p += 64) {
    int r = sedge[p].x;
    float e0 = asrc[r * 2 + 0] + ad0; e0 = e0 > 0.f ? e0 : 0.2f * e0;
    float e1 = asrc[r * 2 + 1] + ad1; e1 = e1 > 0.f ? e1 : 0.2f * e1;
    float a0 = __expf(e0 - m0), a1 = __expf(e1 - m1);
    int i = p - p0;
    if (i < MAXDEG) { lalpha[slot][i][0] = a0; lalpha[slot][i][1] = a1; }
    s0 += a0; s1 += a1;
  }
  #pragma unroll
  for (int o = 32; o > 0; o >>= 1) { s0 += __shfl_xor(s0, o); s1 += __shfl_xor(s1, o); }
  float w0 = __expf(e00 - m0), w1 = __expf(e01 - m1);
  s0 += w0; s1 += w1;
  // aggregate
  int h = l >> 5;
  float swt = h ? w1 : w0;
  float inv_s = 1.f / (h ? s1 : s0);
  const uint2* xv = (const uint2*)XLb;     // row = 64 uint2 (512B)
  uint2 uc = xv[(size_t)c * 64 + l];
  float A0[4] = {swt * bflo(uc.x), swt * bfhi(uc.x), swt * bflo(uc.y), swt * bfhi(uc.y)};
  float A1[4] = {0.f, 0.f, 0.f, 0.f};
  float A2[4] = {0.f, 0.f, 0.f, 0.f};
  float A3[4] = {0.f, 0.f, 0.f, 0.f};
  int deg = p1 - p0;
  int nl = deg < MAXDEG ? deg : MAXDEG;
  int i = 0;
  for (; i + 4 <= nl; i += 4) {
    int r0 = sedge[p0 + i].x,     r1 = sedge[p0 + i + 1].x;
    int r2 = sedge[p0 + i + 2].x, r3 = sedge[p0 + i + 3].x;
    uint2 u0 = xv[(size_t)r0 * 64 + l];
    uint2 u1 = xv[(size_t)r1 * 64 + l];
    uint2 u2 = xv[(size_t)r2 * 64 + l];
    uint2 u3 = xv[(size_t)r3 * 64 + l];
    float al0 = lalpha[slot][i][h],     al1 = lalpha[slot][i + 1][h];
    float al2 = lalpha[slot][i + 2][h], al3 = lalpha[slot][i + 3][h];
    A0[0] += al0 * bflo(u0.x); A0[1] += al0 * bfhi(u0.x); A0[2] += al0 * bflo(u0.y); A0[3] += al0 * bfhi(u0.y);
    A1[0] += al1 * bflo(u1.x); A1[1] += al1 * bfhi(u1.x); A1[2] += al1 * bflo(u1.y); A1[3] += al1 * bfhi(u1.y);
    A2[0] += al2 * bflo(u2.x); A2[1] += al2 * bfhi(u2.x); A2[2] += al2 * bflo(u2.y); A2[3] += al2 * bfhi(u2.y);
    A3[0] += al3 * bflo(u3.x); A3[1] += al3 * bfhi(u3.x); A3[2] += al3 * bflo(u3.y); A3[3] += al3 * bfhi(u3.y);
  }
  for (; i < nl; i++) {
    int r0 = sedge[p0 + i].x;
    uint2 u0 = xv[(size_t)r0 * 64 + l];
    float al = lalpha[slot][i][h];
    A0[0] += al * bflo(u0.x); A0[1] += al * bfhi(u0.x); A0[2] += al * bflo(u0.y); A0[3] += al * bfhi(u0.y);
  }
  // rare tail: deg > MAXDEG -> recompute alpha inline
  for (int p = p0 + MAXDEG; p < p1; p++) {
    int r = sedge[p].x;
    float adh = h ? ad1 : ad0;
    float mh  = h ? m1 : m0;
    float e = asrc[r * 2 + h] + adh; e = e > 0.f ? e : 0.2f * e;
    float al = __expf(e - mh);
    uint2 u0 = xv[(size_t)r * 64 + l];
    A0[0] += al * bflo(u0.x); A0[1] += al * bfhi(u0.x); A0[2] += al * bflo(u0.y); A0[3] += al * bfhi(u0.y);
  }
  float vx = (A0[0] + A1[0] + A2[0] + A3[0]) * inv_s;
  float vy = (A0[1] + A1[1] + A2[1] + A3[1]) * inv_s;
  float vz = (A0[2] + A1[2] + A2[2] + A3[2]) * inv_s;
  float vw = (A0[3] + A1[3] + A2[3] + A3[3]) * inv_s;
  float ox = 0.5f * (vx + __shfl_xor(vx, 32));
  float oy = 0.5f * (vy + __shfl_xor(vy, 32));
  float oz = 0.5f * (vz + __shfl_xor(vz, 32));
  float ow = 0.5f * (vw + __shfl_xor(vw, 32));
  if (l < 32) {
    float4 bb = ((const float4*)b)[l];
    float4 o = make_float4(ox + bb.x, oy + bb.y, oz + bb.z, ow + bb.w);
    if (relu) {
      o.x = fmaxf(o.x, 0.f); o.y = fmaxf(o.y, 0.f);
      o.z = fmaxf(o.z, 0.f); o.w = fmaxf(o.w, 0.f);
    }
    ((float4*)out)[(size_t)c * 32 + l] = o;
  }
}

// ---- gated blend -----------------------------------------------------------
__global__ void blend_kernel(const float* __restrict__ xt, const float* __restrict__ x,
                             const float* __restrict__ fc1W, const float* __restrict__ fc1b,
                             const float* __restrict__ fc2W, const float* __restrict__ fc2b,
                             const float* __restrict__ pb, float* __restrict__ out, int N) {
  int n0 = blockIdx.x * BROWS;
  int j = threadIdx.x;   // 0..127
  __shared__ float xtr[BROWS * C];
  __shared__ float xr[BROWS * C];
  {
    float4* a4 = (float4*)xtr;
    float4* b4 = (float4*)xr;
    const float4* xt4 = (const float4*)xt;
    const float4* x4 = (const float4*)x;
    int tot4 = BROWS * C / 4;    // 512
    for (int i = j; i < tot4; i += 128) {
      int n = n0 + (i * 4) / C;
      if (n < N) {
        a4[i] = xt4[n0 * (C / 4) + i];
        b4[i] = x4[n0 * (C / 4) + i];
      } else {
        a4[i] = make_float4(0.f, 0.f, 0.f, 0.f);
        b4[i] = make_float4(0.f, 0.f, 0.f, 0.f);
      }
    }
  }
  __syncthreads();
  float s1[BROWS], s2[BROWS];
  #pragma unroll
  for (int r = 0; r < BROWS; r++) { s1[r] = 0.f; s2[r] = 0.f; }
  #pragma unroll 2
  for (int k4 = 0; k4 < C; k4 += 4) {
    float w1a = fc1W[(k4 + 0) * C + j], w2a = fc2W[(k4 + 0) * C + j];
    float w1b = fc1W[(k4 + 1) * C + j], w2b = fc2W[(k4 + 1) * C + j];
    float w1c = fc1W[(k4 + 2) * C + j], w2c = fc2W[(k4 + 2) * C + j];
    float w1d = fc1W[(k4 + 3) * C + j], w2d = fc2W[(k4 + 3) * C + j];
    #pragma unroll
    for (int r = 0; r < BROWS; r++) {
      float4 t4 = *(const float4*)&xtr[r * C + k4];
      float4 x4 = *(const float4*)&xr[r * C + k4];
      s1[r] += t4.x * w1a + t4.y * w1b + t4.z * w1c + t4.w * w1d;
      s2[r] += x4.x * w2a + x4.y * w2b + x4.z * w2c + x4.w * w2d;
    }
  }
  float bb = fc1b[j] + fc2b[j] + pb[j];
  for (int r = 0; r < BROWS; r++) {
    int n = n0 + r;
    if (n < N) {
      float t = s1[r] + s2[r] + bb;
      float z = 1.f / (1.f + __expf(-t));
      out[n * C + j] = z * xtr[r * C + j] + (1.f - z) * xr[r * C + j];
    }
  }
}

// ---- launch ----------------------------------------------------------------

extern "C" void kernel_launch(void* const* d_in, const int* in_sizes, int n_in,
                              void* d_out, int out_size, void* d_ws, size_t ws_size,
                              hipStream_t stream) {
  const float* x_in  = (const float*)d_in[0];
  const int*   ei    = (const int*)d_in[1];
  const float* ew    = (const float*)d_in[2];
  const float* gcn_W = (const float*)d_in[3];
  const float* gcn_b = (const float*)d_in[4];
  const float* g1_W  = (const float*)d_in[5];
  const float* g1_as = (const float*)d_in[6];
  const float* g1_ad = (const float*)d_in[7];
  const float* g1_b  = (const float*)d_in[8];
  const float* g2_W  = (const float*)d_in[9];
  const float* g2_as = (const float*)d_in[10];
  const float* g2_ad = (const float*)d_in[11];
  const float* g2_b  = (const float*)d_in[12];
  const float* fc1_W = (const float*)d_in[13];
  const float* fc1_b = (const float*)d_in[14];
  const float* fc2_W = (const float*)d_in[15];
  const float* fc2_b = (const float*)d_in[16];
  const float* pb    = (const float*)d_in[17];

  const int N = in_sizes[0] / F_IN;
  const int E = in_sizes[2];
  const int* row = ei;
  const int* col = ei + E;

  char* ws = (char*)d_ws;
  size_t o = 0;
  auto alloc = [&](size_t bytes) -> void* {
    void* p = ws + o;
    o += (bytes + 255) & ~(size_t)255;
    return p;
  };
  int*   cnt   = (int*)alloc((size_t)(N + 1) * 4);
  int*   cur   = (int*)alloc((size_t)N * 4);
  float* deg   = (float*)alloc((size_t)N * 4);
  size_t zero_bytes = o;                     // cnt+cur+deg at ws start
  int*   off   = (int*)alloc((size_t)(N + 1) * 4);
  float* dinv  = (float*)alloc((size_t)N * 4);
  int*   bsum  = (int*)alloc(256 * 4);
  int2*  sedge = (int2*)alloc((size_t)E * 8);
  float* asrc  = (float*)alloc((size_t)N * 2 * 4);
  float* adst  = (float*)alloc((size_t)N * 2 * 4);
  unsigned short* Ab  = (unsigned short*)alloc((size_t)N * C * 2);       // gcn xl bf16
  unsigned short* XLb = (unsigned short*)alloc((size_t)N * 2 * C * 2);   // gat xl bf16
  float* A     = (float*)alloc((size_t)N * C * 4);      // gat out (xt)
  float* H     = (float*)alloc((size_t)N * C * 4);      // running x
  (void)ws_size; (void)n_in; (void)out_size;

  hipMemsetAsync(d_ws, 0, zero_bytes, stream);

  const int tb = 256;
  const int nP = N + 1;
  const int nb = (nP + 1023) / 1024;
  count_kernel<<<(E + tb - 1) / tb, tb, 0, stream>>>(col, ew, cnt, deg, E);
  scan1_kernel<<<nb, 256, 0, stream>>>(cnt, off, bsum, nP);
  scan2_kernel<<<1, 256, 0, stream>>>(bsum, nb);
  scan3_dinv_kernel<<<(nP + tb - 1) / tb, tb, 0, stream>>>(off, bsum, deg, dinv, nP, N);
  scatter_kernel<<<(E + tb - 1) / tb, tb, 0, stream>>>(row, col, ew, off, dinv, cur, sedge, E);

  // GCN + ReLU
  gemm33_kernel<<<(N + MROWS - 1) / MROWS, C, 0, stream>>>(x_in, gcn_W, Ab, N);
  gcn_agg_kernel<<<(N + 3) / 4, 256, 0, stream>>>(Ab, off, sedge, dinv, gcn_b, H, N);

  // GAT layer 1 (+ReLU) + gated blend (in-place into H)
  gat_gemm_kernel<<<(N + GROWS - 1) / GROWS, C, 0, stream>>>(H, g1_W, g1_as, g1_ad, XLb, asrc, adst, N);
  gat_fused_kernel<<<(N + 3) / 4, 256, 0, stream>>>(XLb, asrc, adst, off, sedge, g1_b, A, 1, N);
  blend_kernel<<<(N + BROWS - 1) / BROWS, C, 0, stream>>>(A, H, fc1_W, fc1_b, fc2_W, fc2_b, pb, H, N);

  // GAT layer 2 (no ReLU) + gated blend into d_out
  gat_gemm_kernel<<<(N + GROWS - 1) / GROWS, C, 0, stream>>>(H, g2_W, g2_as, g2_ad, XLb, asrc, adst, N);
  gat_fused_kernel<<<(N + 3) / 4, 256, 0, stream>>>(XLb, asrc, adst, off, sedge, g2_b, A, 0, N);
  blend_kernel<<<(N + BROWS - 1) / BROWS, C, 0, stream>>>(A, H, fc1_W, fc1_b, fc2_W, fc2_b, pb, (float*)d_out, N);
}

// Round 5
// 1254.174 us; speedup vs baseline: 1.4286x; 1.0052x over previous
//
#include <hip/hip_runtime.h>

#define F_IN 33
#define C 128      // F_OUT
#define GROWS 16   // rows per block in gat_gemm
#define BROWS 16   // rows per block in blend
#define MROWS 8    // rows per block in gemm33
#define MAXDEG 128 // LDS-staged score/alpha cap per node

__device__ __forceinline__ unsigned short f2bf(float f) {
  unsigned u = __float_as_uint(f);
  unsigned r = (u + 0x7fff + ((u >> 16) & 1)) >> 16;   // RNE
  return (unsigned short)r;
}
__device__ __forceinline__ float bflo(unsigned u) { return __uint_as_float(u << 16); }
__device__ __forceinline__ float bfhi(unsigned u) { return __uint_as_float(u & 0xffff0000u); }

// ---- CSR build -------------------------------------------------------------

__global__ void count_kernel(const int* __restrict__ col, const float* __restrict__ w,
                             int* __restrict__ cnt, float* __restrict__ deg, int E) {
  int e = blockIdx.x * blockDim.x + threadIdx.x;
  if (e < E) {
    int c = col[e];
    atomicAdd(&cnt[c], 1);
    atomicAdd(&deg[c], w[e]);
  }
}

__global__ void scan1_kernel(const int* __restrict__ cnt, int* __restrict__ out,
                             int* __restrict__ bsum, int n) {
  __shared__ int lds[256];
  int t = threadIdx.x;
  int base = blockIdx.x * 1024 + t * 4;
  int v0 = (base + 0 < n) ? cnt[base + 0] : 0;
  int v1 = (base + 1 < n) ? cnt[base + 1] : 0;
  int v2 = (base + 2 < n) ? cnt[base + 2] : 0;
  int v3 = (base + 3 < n) ? cnt[base + 3] : 0;
  int tot = v0 + v1 + v2 + v3;
  lds[t] = tot;
  __syncthreads();
  for (int o = 1; o < 256; o <<= 1) {
    int x = (t >= o) ? lds[t - o] : 0;
    __syncthreads();
    lds[t] += x;
    __syncthreads();
  }
  int excl = lds[t] - tot;
  if (t == 255) bsum[blockIdx.x] = lds[255];
  if (base + 0 < n) out[base + 0] = excl;
  if (base + 1 < n) out[base + 1] = excl + v0;
  if (base + 2 < n) out[base + 2] = excl + v0 + v1;
  if (base + 3 < n) out[base + 3] = excl + v0 + v1 + v2;
}

__global__ void scan2_kernel(int* __restrict__ bsum, int nb) {
  __shared__ int lds[256];
  int t = threadIdx.x;
  int v = (t < nb) ? bsum[t] : 0;
  lds[t] = v;
  __syncthreads();
  for (int o = 1; o < 256; o <<= 1) {
    int x = (t >= o) ? lds[t - o] : 0;
    __syncthreads();
    lds[t] += x;
    __syncthreads();
  }
  if (t < nb) bsum[t] = lds[t] - v;
}

__global__ void scan3_dinv_kernel(int* __restrict__ off, const int* __restrict__ bsum,
                                  const float* __restrict__ deg, float* __restrict__ dinv,
                                  int n, int N) {
  int i = blockIdx.x * blockDim.x + threadIdx.x;
  if (i < n) off[i] += bsum[i >> 10];
  if (i < N) dinv[i] = rsqrtf(deg[i] + 1.0f);
}

__global__ void scatter_kernel(const int* __restrict__ row, const int* __restrict__ col,
                               const float* __restrict__ w, const int* __restrict__ off,
                               const float* __restrict__ dinv, int* __restrict__ cur,
                               int2* __restrict__ sedge, int E) {
  int e = blockIdx.x * blockDim.x + threadIdx.x;
  if (e < E) {
    int c = col[e];
    int r = row[e];
    int p = off[c] + atomicAdd(&cur[c], 1);
    sedge[p] = make_int2(r, __float_as_int(dinv[r] * w[e]));
  }
}

// ---- GCN -------------------------------------------------------------------

__global__ void gemm33_kernel(const float* __restrict__ x, const float* __restrict__ W,
                              unsigned short* __restrict__ out, int N) {
  int n0 = blockIdx.x * MROWS;
  int t = threadIdx.x;   // 0..127
  __shared__ float xr[MROWS * F_IN];
  for (int i = t; i < MROWS * F_IN; i += 128) {
    int idx = n0 * F_IN + i;
    xr[i] = (idx < N * F_IN) ? x[idx] : 0.f;
  }
  __syncthreads();
  float acc[MROWS];
  #pragma unroll
  for (int r = 0; r < MROWS; r++) acc[r] = 0.f;
  #pragma unroll
  for (int k = 0; k < F_IN; k++) {
    float wv = W[k * C + t];
    #pragma unroll
    for (int r = 0; r < MROWS; r++) acc[r] += xr[r * F_IN + k] * wv;
  }
  for (int r = 0; r < MROWS; r++) {
    int n = n0 + r;
    if (n < N) out[n * C + t] = f2bf(acc[r]);
  }
}

// 4 nodes/block, one wave each; bf16 gather (256B/edge), 8-deep unroll
__global__ __launch_bounds__(256) void gcn_agg_kernel(
    const unsigned short* __restrict__ Ab, const int* __restrict__ off,
    const int2* __restrict__ sedge, const float* __restrict__ dinv,
    const float* __restrict__ b, float* __restrict__ out, int N) {
  int c = blockIdx.x * 4 + (threadIdx.x >> 6);
  if (c >= N) return;
  int l = threadIdx.x & 63;
  const unsigned* xv = (const unsigned*)Ab;   // row = 64 dwords (256B)
  float dc = dinv[c];
  unsigned uc = xv[(size_t)c * 64 + l];
  float A0x = dc * bflo(uc), A0y = dc * bfhi(uc);
  float A1x = 0.f, A1y = 0.f, A2x = 0.f, A2y = 0.f, A3x = 0.f, A3y = 0.f;
  int p = off[c], p1 = off[c + 1];
  for (; p + 8 <= p1; p += 8) {
    int2 e0 = sedge[p + 0], e1 = sedge[p + 1], e2 = sedge[p + 2], e3 = sedge[p + 3];
    int2 e4 = sedge[p + 4], e5 = sedge[p + 5], e6 = sedge[p + 6], e7 = sedge[p + 7];
    unsigned u0 = xv[(size_t)e0.x * 64 + l];
    unsigned u1 = xv[(size_t)e1.x * 64 + l];
    unsigned u2 = xv[(size_t)e2.x * 64 + l];
    unsigned u3 = xv[(size_t)e3.x * 64 + l];
    unsigned u4 = xv[(size_t)e4.x * 64 + l];
    unsigned u5 = xv[(size_t)e5.x * 64 + l];
    unsigned u6 = xv[(size_t)e6.x * 64 + l];
    unsigned u7 = xv[(size_t)e7.x * 64 + l];
    float w0 = __int_as_float(e0.y), w1 = __int_as_float(e1.y);
    float w2 = __int_as_float(e2.y), w3 = __int_as_float(e3.y);
    float w4 = __int_as_float(e4.y), w5 = __int_as_float(e5.y);
    float w6 = __int_as_float(e6.y), w7 = __int_as_float(e7.y);
    A0x += w0 * bflo(u0); A0y += w0 * bfhi(u0);
    A1x += w1 * bflo(u1); A1y += w1 * bfhi(u1);
    A2x += w2 * bflo(u2); A2y += w2 * bfhi(u2);
    A3x += w3 * bflo(u3); A3y += w3 * bfhi(u3);
    A0x += w4 * bflo(u4); A0y += w4 * bfhi(u4);
    A1x += w5 * bflo(u5); A1y += w5 * bfhi(u5);
    A2x += w6 * bflo(u6); A2y += w6 * bfhi(u6);
    A3x += w7 * bflo(u7); A3y += w7 * bfhi(u7);
  }
  for (; p < p1; p++) {
    int2 e0 = sedge[p];
    unsigned u0 = xv[(size_t)e0.x * 64 + l];
    float w0 = __int_as_float(e0.y);
    A0x += w0 * bflo(u0); A0y += w0 * bfhi(u0);
  }
  float2 bb = ((const float2*)b)[l];
  float2 o;
  o.x = fmaxf(dc * (A0x + A1x + A2x + A3x) + bb.x, 0.f);
  o.y = fmaxf(dc * (A0y + A1y + A2y + A3y) + bb.y, 0.f);
  ((float2*)out)[(size_t)c * 64 + l] = o;
}

// ---- GAT -------------------------------------------------------------------

__global__ void gat_gemm_kernel(const float* __restrict__ x, const float* __restrict__ W,
                                const float* __restrict__ as, const float* __restrict__ ad,
                                unsigned short* __restrict__ XLb, float* __restrict__ asrc,
                                float* __restrict__ adst, int N) {
  int n0 = blockIdx.x * GROWS;
  int j = threadIdx.x;   // 0..127
  __shared__ float xr[GROWS * C];          // 8 KB
  __shared__ float xls[GROWS * 264];       // 16.5 KB
  {
    float4* xr4 = (float4*)xr;
    const float4* x4 = (const float4*)x;
    int tot4 = GROWS * C / 4;              // 512
    for (int i = j; i < tot4; i += 128) {
      int n = n0 + (i * 4) / C;
      xr4[i] = (n < N) ? x4[n0 * (C / 4) + i] : make_float4(0.f, 0.f, 0.f, 0.f);
    }
  }
  __syncthreads();
  float acc0[GROWS], acc1[GROWS];
  #pragma unroll
  for (int r = 0; r < GROWS; r++) { acc0[r] = 0.f; acc1[r] = 0.f; }
  #pragma unroll 2
  for (int k4 = 0; k4 < C; k4 += 4) {
    float wa0 = W[(k4 + 0) * 2 * C + j],       wb0 = W[(k4 + 0) * 2 * C + j + C];
    float wa1 = W[(k4 + 1) * 2 * C + j],       wb1 = W[(k4 + 1) * 2 * C + j + C];
    float wa2 = W[(k4 + 2) * 2 * C + j],       wb2 = W[(k4 + 2) * 2 * C + j + C];
    float wa3 = W[(k4 + 3) * 2 * C + j],       wb3 = W[(k4 + 3) * 2 * C + j + C];
    #pragma unroll
    for (int r = 0; r < GROWS; r++) {
      float4 xv = *(const float4*)&xr[r * C + k4];
      acc0[r] += xv.x * wa0 + xv.y * wa1 + xv.z * wa2 + xv.w * wa3;
      acc1[r] += xv.x * wb0 + xv.y * wb1 + xv.z * wb2 + xv.w * wb3;
    }
  }
  #pragma unroll
  for (int r = 0; r < GROWS; r++) {
    int n = n0 + r;
    xls[r * 264 + j] = acc0[r];
    xls[r * 264 + C + j] = acc1[r];
    if (n < N) {
      XLb[(size_t)n * 2 * C + j]     = f2bf(acc0[r]);
      XLb[(size_t)n * 2 * C + C + j] = f2bf(acc1[r]);
    }
  }
  __syncthreads();
  int r = j >> 3, sub = j & 7;
  float sa0 = 0.f, sd0 = 0.f, sa1 = 0.f, sd1 = 0.f;
  for (int k = sub; k < C; k += 8) {
    float v0 = xls[r * 264 + k];
    float v1 = xls[r * 264 + C + k];
    sa0 += v0 * as[k];      sd0 += v0 * ad[k];
    sa1 += v1 * as[C + k];  sd1 += v1 * ad[C + k];
  }
  #pragma unroll
  for (int o = 4; o > 0; o >>= 1) {
    sa0 += __shfl_down(sa0, o); sd0 += __shfl_down(sd0, o);
    sa1 += __shfl_down(sa1, o); sd1 += __shfl_down(sd1, o);
  }
  int n = n0 + r;
  if (sub == 0 && n < N) {
    asrc[n * 2 + 0] = sa0; adst[n * 2 + 0] = sd0;
    asrc[n * 2 + 1] = sa1; adst[n * 2 + 1] = sd1;
  }
}

// fused edge-softmax + aggregate + head-mean. 4 nodes/block, 1 wave/node.
// Single gather pass for scores (stored in LDS, exp-converted after max).
__global__ __launch_bounds__(256) void gat_fused_kernel(
    const unsigned short* __restrict__ XLb,
    const float* __restrict__ asrc, const float* __restrict__ adst,
    const int* __restrict__ off, const int2* __restrict__ sedge,
    const float* __restrict__ b, float* __restrict__ out,
    int relu, int N) {
  __shared__ float lsc[4][MAXDEG][2];   // scores -> alphas; 4 KB
  int slot = threadIdx.x >> 6;
  int c = blockIdx.x * 4 + slot;
  if (c >= N) return;                   // wave-local LDS use only, no barriers
  int l = threadIdx.x & 63;
  float ad0 = adst[c * 2 + 0], ad1 = adst[c * 2 + 1];
  int p0 = off[c], p1 = off[c + 1];
  int deg = p1 - p0;
  float e00 = asrc[c * 2 + 0] + ad0; e00 = e00 > 0.f ? e00 : 0.2f * e00;
  float e01 = asrc[c * 2 + 1] + ad1; e01 = e01 > 0.f ? e01 : 0.2f * e01;
  float m0 = e00, m1 = e01;
  // pass 1: gather scores once, stash in LDS, running max
  for (int p = p0 + l; p < p1; p += 64) {
    int r = sedge[p].x;
    float2 av = ((const float2*)asrc)[r];
    float e0 = av.x + ad0; e0 = e0 > 0.f ? e0 : 0.2f * e0;
    float e1 = av.y + ad1; e1 = e1 > 0.f ? e1 : 0.2f * e1;
    int i = p - p0;
    if (i < MAXDEG) { lsc[slot][i][0] = e0; lsc[slot][i][1] = e1; }
    m0 = fmaxf(m0, e0); m1 = fmaxf(m1, e1);
  }
  #pragma unroll
  for (int o = 32; o > 0; o >>= 1) {
    m0 = fmaxf(m0, __shfl_xor(m0, o));
    m1 = fmaxf(m1, __shfl_xor(m1, o));
  }
  // pass 2 (LDS only): exp-convert in place + partial sums
  int nl = deg < MAXDEG ? deg : MAXDEG;
  float s0 = 0.f, s1 = 0.f;
  for (int i = l; i < nl; i += 64) {
    float a0 = __expf(lsc[slot][i][0] - m0);
    float a1 = __expf(lsc[slot][i][1] - m1);
    lsc[slot][i][0] = a0; lsc[slot][i][1] = a1;
    s0 += a0; s1 += a1;
  }
  // rare tail (deg > MAXDEG): recompute for the sum
  for (int p = p0 + MAXDEG + l; p < p1; p += 64) {
    int r = sedge[p].x;
    float2 av = ((const float2*)asrc)[r];
    float e0 = av.x + ad0; e0 = e0 > 0.f ? e0 : 0.2f * e0;
    float e1 = av.y + ad1; e1 = e1 > 0.f ? e1 : 0.2f * e1;
    s0 += __expf(e0 - m0); s1 += __expf(e1 - m1);
  }
  #pragma unroll
  for (int o = 32; o > 0; o >>= 1) { s0 += __shfl_xor(s0, o); s1 += __shfl_xor(s1, o); }
  float w0 = __expf(e00 - m0), w1 = __expf(e01 - m1);
  s0 += w0; s1 += w1;
  // aggregate: 8-deep gather unroll, 4 paired acc chains
  int h = l >> 5;
  float swt = h ? w1 : w0;
  float inv_s = 1.f / (h ? s1 : s0);
  const uint2* xv = (const uint2*)XLb;     // row = 64 uint2 (512B)
  uint2 uc = xv[(size_t)c * 64 + l];
  float A0[4] = {swt * bflo(uc.x), swt * bfhi(uc.x), swt * bflo(uc.y), swt * bfhi(uc.y)};
  float A1[4] = {0.f, 0.f, 0.f, 0.f};
  float A2[4] = {0.f, 0.f, 0.f, 0.f};
  float A3[4] = {0.f, 0.f, 0.f, 0.f};
  int i = 0;
  for (; i + 8 <= nl; i += 8) {
    int r0 = sedge[p0 + i + 0].x, r1 = sedge[p0 + i + 1].x;
    int r2 = sedge[p0 + i + 2].x, r3 = sedge[p0 + i + 3].x;
    int r4 = sedge[p0 + i + 4].x, r5 = sedge[p0 + i + 5].x;
    int r6 = sedge[p0 + i + 6].x, r7 = sedge[p0 + i + 7].x;
    uint2 u0 = xv[(size_t)r0 * 64 + l];
    uint2 u1 = xv[(size_t)r1 * 64 + l];
    uint2 u2 = xv[(size_t)r2 * 64 + l];
    uint2 u3 = xv[(size_t)r3 * 64 + l];
    uint2 u4 = xv[(size_t)r4 * 64 + l];
    uint2 u5 = xv[(size_t)r5 * 64 + l];
    uint2 u6 = xv[(size_t)r6 * 64 + l];
    uint2 u7 = xv[(size_t)r7 * 64 + l];
    float al0 = lsc[slot][i + 0][h], al1 = lsc[slot][i + 1][h];
    float al2 = lsc[slot][i + 2][h], al3 = lsc[slot][i + 3][h];
    float al4 = lsc[slot][i + 4][h], al5 = lsc[slot][i + 5][h];
    float al6 = lsc[slot][i + 6][h], al7 = lsc[slot][i + 7][h];
    A0[0] += al0 * bflo(u0.x); A0[1] += al0 * bfhi(u0.x); A0[2] += al0 * bflo(u0.y); A0[3] += al0 * bfhi(u0.y);
    A1[0] += al1 * bflo(u1.x); A1[1] += al1 * bfhi(u1.x); A1[2] += al1 * bflo(u1.y); A1[3] += al1 * bfhi(u1.y);
    A2[0] += al2 * bflo(u2.x); A2[1] += al2 * bfhi(u2.x); A2[2] += al2 * bflo(u2.y); A2[3] += al2 * bfhi(u2.y);
    A3[0] += al3 * bflo(u3.x); A3[1] += al3 * bfhi(u3.x); A3[2] += al3 * bflo(u3.y); A3[3] += al3 * bfhi(u3.y);
    A0[0] += al4 * bflo(u4.x); A0[1] += al4 * bfhi(u4.x); A0[2] += al4 * bflo(u4.y); A0[3] += al4 * bfhi(u4.y);
    A1[0] += al5 * bflo(u5.x); A1[1] += al5 * bfhi(u5.x); A1[2] += al5 * bflo(u5.y); A1[3] += al5 * bfhi(u5.y);
    A2[0] += al6 * bflo(u6.x); A2[1] += al6 * bfhi(u6.x); A2[2] += al6 * bflo(u6.y); A2[3] += al6 * bfhi(u6.y);
    A3[0] += al7 * bflo(u7.x); A3[1] += al7 * bfhi(u7.x); A3[2] += al7 * bflo(u7.y); A3[3] += al7 * bfhi(u7.y);
  }
  for (; i < nl; i++) {
    int r0 = sedge[p0 + i].x;
    uint2 u0 = xv[(size_t)r0 * 64 + l];
    float al = lsc[slot][i][h];
    A0[0] += al * bflo(u0.x); A0[1] += al * bfhi(u0.x); A0[2] += al * bflo(u0.y); A0[3] += al * bfhi(u0.y);
  }
  // rare tail: deg > MAXDEG -> recompute alpha inline
  for (int p = p0 + MAXDEG; p < p1; p++) {
    int r = sedge[p].x;
    float adh = h ? ad1 : ad0;
    float mh  = h ? m1 : m0;
    float e = asrc[r * 2 + h] + adh; e = e > 0.f ? e : 0.2f * e;
    float al = __expf(e - mh);
    uint2 u0 = xv[(size_t)r * 64 + l];
    A0[0] += al * bflo(u0.x); A0[1] += al * bfhi(u0.x); A0[2] += al * bflo(u0.y); A0[3] += al * bfhi(u0.y);
  }
  float vx = (A0[0] + A1[0] + A2[0] + A3[0]) * inv_s;
  float vy = (A0[1] + A1[1] + A2[1] + A3[1]) * inv_s;
  float vz = (A0[2] + A1[2] + A2[2] + A3[2]) * inv_s;
  float vw = (A0[3] + A1[3] + A2[3] + A3[3]) * inv_s;
  float ox = 0.5f * (vx + __shfl_xor(vx, 32));
  float oy = 0.5f * (vy + __shfl_xor(vy, 32));
  float oz = 0.5f * (vz + __shfl_xor(vz, 32));
  float ow = 0.5f * (vw + __shfl_xor(vw, 32));
  if (l < 32) {
    float4 bb = ((const float4*)b)[l];
    float4 o = make_float4(ox + bb.x, oy + bb.y, oz + bb.z, ow + bb.w);
    if (relu) {
      o.x = fmaxf(o.x, 0.f); o.y = fmaxf(o.y, 0.f);
      o.z = fmaxf(o.z, 0.f); o.w = fmaxf(o.w, 0.f);
    }
    ((float4*)out)[(size_t)c * 32 + l] = o;
  }
}

// ---- gated blend -----------------------------------------------------------
__global__ void blend_kernel(const float* __restrict__ xt, const float* __restrict__ x,
                             const float* __restrict__ fc1W, const float* __restrict__ fc1b,
                             const float* __restrict__ fc2W, const float* __restrict__ fc2b,
                             const float* __restrict__ pb, float* __restrict__ out, int N) {
  int n0 = blockIdx.x * BROWS;
  int j = threadIdx.x;   // 0..127
  __shared__ float xtr[BROWS * C];
  __shared__ float xr[BROWS * C];
  {
    float4* a4 = (float4*)xtr;
    float4* b4 = (float4*)xr;
    const float4* xt4 = (const float4*)xt;
    const float4* x4 = (const float4*)x;
    int tot4 = BROWS * C / 4;    // 512
    for (int i = j; i < tot4; i += 128) {
      int n = n0 + (i * 4) / C;
      if (n < N) {
        a4[i] = xt4[n0 * (C / 4) + i];
        b4[i] = x4[n0 * (C / 4) + i];
      } else {
        a4[i] = make_float4(0.f, 0.f, 0.f, 0.f);
        b4[i] = make_float4(0.f, 0.f, 0.f, 0.f);
      }
    }
  }
  __syncthreads();
  float s1[BROWS], s2[BROWS];
  #pragma unroll
  for (int r = 0; r < BROWS; r++) { s1[r] = 0.f; s2[r] = 0.f; }
  #pragma unroll 2
  for (int k4 = 0; k4 < C; k4 += 4) {
    float w1a = fc1W[(k4 + 0) * C + j], w2a = fc2W[(k4 + 0) * C + j];
    float w1b = fc1W[(k4 + 1) * C + j], w2b = fc2W[(k4 + 1) * C + j];
    float w1c = fc1W[(k4 + 2) * C + j], w2c = fc2W[(k4 + 2) * C + j];
    float w1d = fc1W[(k4 + 3) * C + j], w2d = fc2W[(k4 + 3) * C + j];
    #pragma unroll
    for (int r = 0; r < BROWS; r++) {
      float4 t4 = *(const float4*)&xtr[r * C + k4];
      float4 x4 = *(const float4*)&xr[r * C + k4];
      s1[r] += t4.x * w1a + t4.y * w1b + t4.z * w1c + t4.w * w1d;
      s2[r] += x4.x * w2a + x4.y * w2b + x4.z * w2c + x4.w * w2d;
    }
  }
  float bb = fc1b[j] + fc2b[j] + pb[j];
  for (int r = 0; r < BROWS; r++) {
    int n = n0 + r;
    if (n < N) {
      float t = s1[r] + s2[r] + bb;
      float z = 1.f / (1.f + __expf(-t));
      out[n * C + j] = z * xtr[r * C + j] + (1.f - z) * xr[r * C + j];
    }
  }
}

// ---- launch ----------------------------------------------------------------

extern "C" void kernel_launch(void* const* d_in, const int* in_sizes, int n_in,
                              void* d_out, int out_size, void* d_ws, size_t ws_size,
                              hipStream_t stream) {
  const float* x_in  = (const float*)d_in[0];
  const int*   ei    = (const int*)d_in[1];
  const float* ew    = (const float*)d_in[2];
  const float* gcn_W = (const float*)d_in[3];
  const float* gcn_b = (const float*)d_in[4];
  const float* g1_W  = (const float*)d_in[5];
  const float* g1_as = (const float*)d_in[6];
  const float* g1_ad = (const float*)d_in[7];
  const float* g1_b  = (const float*)d_in[8];
  const float* g2_W  = (const float*)d_in[9];
  const float* g2_as = (const float*)d_in[10];
  const float* g2_ad = (const float*)d_in[11];
  const float* g2_b  = (const float*)d_in[12];
  const float* fc1_W = (const float*)d_in[13];
  const float* fc1_b = (const float*)d_in[14];
  const float* fc2_W = (const float*)d_in[15];
  const float* fc2_b = (const float*)d_in[16];
  const float* pb    = (const float*)d_in[17];

  const int N = in_sizes[0] / F_IN;
  const int E = in_sizes[2];
  const int* row = ei;
  const int* col = ei + E;

  char* ws = (char*)d_ws;
  size_t o = 0;
  auto alloc = [&](size_t bytes) -> void* {
    void* p = ws + o;
    o += (bytes + 255) & ~(size_t)255;
    return p;
  };
  int*   cnt   = (int*)alloc((size_t)(N + 1) * 4);
  int*   cur   = (int*)alloc((size_t)N * 4);
  float* deg   = (float*)alloc((size_t)N * 4);
  size_t zero_bytes = o;                     // cnt+cur+deg at ws start
  int*   off   = (int*)alloc((size_t)(N + 1) * 4);
  float* dinv  = (float*)alloc((size_t)N * 4);
  int*   bsum  = (int*)alloc(256 * 4);
  int2*  sedge = (int2*)alloc((size_t)E * 8);
  float* asrc  = (float*)alloc((size_t)N * 2 * 4);
  float* adst  = (float*)alloc((size_t)N * 2 * 4);
  unsigned short* Ab  = (unsigned short*)alloc((size_t)N * C * 2);       // gcn xl bf16
  unsigned short* XLb = (unsigned short*)alloc((size_t)N * 2 * C * 2);   // gat xl bf16
  float* A     = (float*)alloc((size_t)N * C * 4);      // gat out (xt)
  float* H     = (float*)alloc((size_t)N * C * 4);      // running x
  (void)ws_size; (void)n_in; (void)out_size;

  hipMemsetAsync(d_ws, 0, zero_bytes, stream);

  const int tb = 256;
  const int nP = N + 1;
  const int nb = (nP + 1023) / 1024;
  count_kernel<<<(E + tb - 1) / tb, tb, 0, stream>>>(col, ew, cnt, deg, E);
  scan1_kernel<<<nb, 256, 0, stream>>>(cnt, off, bsum, nP);
  scan2_kernel<<<1, 256, 0, stream>>>(bsum, nb);
  scan3_dinv_kernel<<<(nP + tb - 1) / tb, tb, 0, stream>>>(off, bsum, deg, dinv, nP, N);
  scatter_kernel<<<(E + tb - 1) / tb, tb, 0, stream>>>(row, col, ew, off, dinv, cur, sedge, E);

  // GCN + ReLU
  gemm33_kernel<<<(N + MROWS - 1) / MROWS, C, 0, stream>>>(x_in, gcn_W, Ab, N);
  gcn_agg_kernel<<<(N + 3) / 4, 256, 0, stream>>>(Ab, off, sedge, dinv, gcn_b, H, N);

  // GAT layer 1 (+ReLU) + gated blend (in-place into H)
  gat_gemm_kernel<<<(N + GROWS - 1) / GROWS, C, 0, stream>>>(H, g1_W, g1_as, g1_ad, XLb, asrc, adst, N);
  gat_fused_kernel<<<(N + 3) / 4, 256, 0, stream>>>(XLb, asrc, adst, off, sedge, g1_b, A, 1, N);
  blend_kernel<<<(N + BROWS - 1) / BROWS, C, 0, stream>>>(A, H, fc1_W, fc1_b, fc2_W, fc2_b, pb, H, N);

  // GAT layer 2 (no ReLU) + gated blend into d_out
  gat_gemm_kernel<<<(N + GROWS - 1) / GROWS, C, 0, stream>>>(H, g2_W, g2_as, g2_ad, XLb, asrc, adst, N);
  gat_fused_kernel<<<(N + 3) / 4, 256, 0, stream>>>(XLb, asrc, adst, off, sedge, g2_b, A, 0, N);
  blend_kernel<<<(N + BROWS - 1) / BROWS, C, 0, stream>>>(A, H, fc1_W, fc1_b, fc2_W, fc2_b, pb, (float*)d_out, N);
}

// Round 6
// 1006.958 us; speedup vs baseline: 1.7793x; 1.2455x over previous
//
#include <hip/hip_runtime.h>

#define F_IN 33
#define FP 36      // padded input cols for gcn gather (18 uints)
#define C 128      // F_OUT
#define GROWS 16   // rows per block in dense kernels
#define MAXDEG 128 // LDS-staged score/alpha cap per node

__device__ __forceinline__ unsigned short f2bf(float f) {
  unsigned u = __float_as_uint(f);
  unsigned r = (u + 0x7fff + ((u >> 16) & 1)) >> 16;   // RNE
  return (unsigned short)r;
}
__device__ __forceinline__ unsigned pack2(float lo, float hi) {
  return (unsigned)f2bf(lo) | ((unsigned)f2bf(hi) << 16);
}
__device__ __forceinline__ float bflo(unsigned u) { return __uint_as_float(u << 16); }
__device__ __forceinline__ float bfhi(unsigned u) { return __uint_as_float(u & 0xffff0000u); }

// ---- CSR build -------------------------------------------------------------

__global__ void count_kernel(const int* __restrict__ col, const float* __restrict__ w,
                             int* __restrict__ cnt, float* __restrict__ deg, int E) {
  int e = blockIdx.x * blockDim.x + threadIdx.x;
  if (e < E) {
    int c = col[e];
    atomicAdd(&cnt[c], 1);
    atomicAdd(&deg[c], w[e]);
  }
}

__global__ void scan1_kernel(const int* __restrict__ cnt, int* __restrict__ out,
                             int* __restrict__ bsum, int n) {
  __shared__ int lds[256];
  int t = threadIdx.x;
  int base = blockIdx.x * 1024 + t * 4;
  int v0 = (base + 0 < n) ? cnt[base + 0] : 0;
  int v1 = (base + 1 < n) ? cnt[base + 1] : 0;
  int v2 = (base + 2 < n) ? cnt[base + 2] : 0;
  int v3 = (base + 3 < n) ? cnt[base + 3] : 0;
  int tot = v0 + v1 + v2 + v3;
  lds[t] = tot;
  __syncthreads();
  for (int o = 1; o < 256; o <<= 1) {
    int x = (t >= o) ? lds[t - o] : 0;
    __syncthreads();
    lds[t] += x;
    __syncthreads();
  }
  int excl = lds[t] - tot;
  if (t == 255) bsum[blockIdx.x] = lds[255];
  if (base + 0 < n) out[base + 0] = excl;
  if (base + 1 < n) out[base + 1] = excl + v0;
  if (base + 2 < n) out[base + 2] = excl + v0 + v1;
  if (base + 3 < n) out[base + 3] = excl + v0 + v1 + v2;
}

__global__ void scan2_kernel(int* __restrict__ bsum, int nb) {
  __shared__ int lds[256];
  int t = threadIdx.x;
  int v = (t < nb) ? bsum[t] : 0;
  lds[t] = v;
  __syncthreads();
  for (int o = 1; o < 256; o <<= 1) {
    int x = (t >= o) ? lds[t - o] : 0;
    __syncthreads();
    lds[t] += x;
    __syncthreads();
  }
  if (t < nb) bsum[t] = lds[t] - v;
}

__global__ void scan3_dinv_kernel(int* __restrict__ off, const int* __restrict__ bsum,
                                  const float* __restrict__ deg, float* __restrict__ dinv,
                                  int n, int N) {
  int i = blockIdx.x * blockDim.x + threadIdx.x;
  if (i < n) off[i] += bsum[i >> 10];
  if (i < N) dinv[i] = rsqrtf(deg[i] + 1.0f);
}

__global__ void scatter_kernel(const int* __restrict__ row, const int* __restrict__ col,
                               const float* __restrict__ w, const int* __restrict__ off,
                               const float* __restrict__ dinv, int* __restrict__ cur,
                               int2* __restrict__ sedge, int E) {
  int e = blockIdx.x * blockDim.x + threadIdx.x;
  if (e < E) {
    int c = col[e];
    int r = row[e];
    int p = off[c] + atomicAdd(&cur[c], 1);
    sedge[p] = make_int2(r, __float_as_int(dinv[r] * w[e]));
  }
}

// ---- parameter prep --------------------------------------------------------

// attv[layer*512 + sd*256 + h*128 + k] = sum_c W[k, h*128+c] * att[h,c]
__global__ void prep_dots_kernel(const float* __restrict__ W1, const float* __restrict__ as1,
                                 const float* __restrict__ ad1, const float* __restrict__ W2,
                                 const float* __restrict__ as2, const float* __restrict__ ad2,
                                 float* __restrict__ attv) {
  int t = blockIdx.x * 256 + threadIdx.x;
  if (t >= 1024) return;
  int layer = t >> 9, rem = t & 511, sd = rem >> 8, rem2 = rem & 255;
  int h = rem2 >> 7, k = rem2 & 127;
  const float* W = layer ? W2 : W1;
  const float* att = sd ? (layer ? ad2 : ad1) : (layer ? as2 : as1);
  float s = 0.f;
  for (int c2 = 0; c2 < C; c2++) s += W[k * 2 * C + h * C + c2] * att[h * C + c2];
  attv[t] = s;
}

// Wp[(h*128+k)*128 + j] = W[k, h*128+j]  (so post-GEMM K axis is (h,k))
__global__ void prep_repack_kernel(const float* __restrict__ W1, const float* __restrict__ W2,
                                   float* __restrict__ Wp1, float* __restrict__ Wp2) {
  int t = blockIdx.x * 256 + threadIdx.x;   // 0..65535
  int layer = t >> 15, rem = t & 32767, hk = rem >> 7, j = rem & 127;
  int h = hk >> 7, k = hk & 127;
  const float* W = layer ? W2 : W1;
  float* Wp = layer ? Wp2 : Wp1;
  Wp[hk * C + j] = W[k * 2 * C + h * C + j];
}

// x_in [N,33] f32 -> X36 [N,36] bf16 (pad 0); one uint (2 cols) per thread
__global__ void convert_x_kernel(const float* __restrict__ x, unsigned* __restrict__ X36U, int N) {
  int t = blockIdx.x * blockDim.x + threadIdx.x;
  if (t >= N * (FP / 2)) return;
  int n = t / (FP / 2);
  int p = t - n * (FP / 2);
  int c0 = 2 * p, c1 = 2 * p + 1;
  float f0 = (c0 < F_IN) ? x[n * F_IN + c0] : 0.f;
  float f1 = (c1 < F_IN) ? x[n * F_IN + c1] : 0.f;
  X36U[t] = pack2(f0, f1);
}

// ---- GCN (aggregate-then-project) -----------------------------------------

// Xagg[c] = dc * ( sum_e w_e * x36[r] + dc * x36[c] ); 4 nodes/block, 1 wave each
__global__ __launch_bounds__(256) void gcn_agg33_kernel(
    const unsigned* __restrict__ X36U, const int* __restrict__ off,
    const int2* __restrict__ sedge, const float* __restrict__ dinv,
    float* __restrict__ Xagg, int N) {
  int c = blockIdx.x * 4 + (threadIdx.x >> 6);
  if (c >= N) return;
  int l = threadIdx.x & 63;
  bool act = l < FP / 2;   // 18 active gather lanes
  float dc = dinv[c];
  unsigned uc = act ? X36U[(unsigned)c * (FP / 2) + l] : 0u;
  float A0x = dc * bflo(uc), A0y = dc * bfhi(uc);
  float A1x = 0.f, A1y = 0.f, A2x = 0.f, A2y = 0.f, A3x = 0.f, A3y = 0.f;
  int p = off[c], p1 = off[c + 1];
  for (; p + 4 <= p1; p += 4) {
    int2 e0 = sedge[p + 0], e1 = sedge[p + 1], e2 = sedge[p + 2], e3 = sedge[p + 3];
    unsigned u0 = 0, u1 = 0, u2 = 0, u3 = 0;
    if (act) {
      u0 = X36U[(unsigned)e0.x * (FP / 2) + l];
      u1 = X36U[(unsigned)e1.x * (FP / 2) + l];
      u2 = X36U[(unsigned)e2.x * (FP / 2) + l];
      u3 = X36U[(unsigned)e3.x * (FP / 2) + l];
    }
    float w0 = __int_as_float(e0.y), w1 = __int_as_float(e1.y);
    float w2 = __int_as_float(e2.y), w3 = __int_as_float(e3.y);
    A0x += w0 * bflo(u0); A0y += w0 * bfhi(u0);
    A1x += w1 * bflo(u1); A1y += w1 * bfhi(u1);
    A2x += w2 * bflo(u2); A2y += w2 * bfhi(u2);
    A3x += w3 * bflo(u3); A3y += w3 * bfhi(u3);
  }
  for (; p < p1; p++) {
    int2 e0 = sedge[p];
    unsigned u0 = act ? X36U[(unsigned)e0.x * (FP / 2) + l] : 0u;
    float w0 = __int_as_float(e0.y);
    A0x += w0 * bflo(u0); A0y += w0 * bfhi(u0);
  }
  if (act) {
    float2 o;
    o.x = dc * (A0x + A1x + A2x + A3x);
    o.y = dc * (A0y + A1y + A2y + A3y);
    ((float2*)Xagg)[(unsigned)c * (FP / 2) + l] = o;
  }
}

// H = relu(Xagg @ W33 + b); also emits Hb (bf16) and score dots asrc/adst
__global__ void gemm36_kernel(const float* __restrict__ Xagg, const float* __restrict__ W,
                              const float* __restrict__ b, const float* __restrict__ ws,
                              const float* __restrict__ wd, float* __restrict__ H,
                              unsigned short* __restrict__ Hb, float* __restrict__ asrc,
                              float* __restrict__ adst, int N) {
  int n0 = blockIdx.x * GROWS;
  int j = threadIdx.x;   // 0..127
  __shared__ float xr[GROWS * FP];    // 2.3 KB
  __shared__ float xls[GROWS * 132];  // 8.4 KB
  {
    const float4* src = (const float4*)(Xagg + (size_t)n0 * FP);
    float4* dst = (float4*)xr;
    for (int i = j; i < GROWS * FP / 4; i += 128) dst[i] = src[i];  // N%16==0
  }
  __syncthreads();
  float acc[GROWS];
  #pragma unroll
  for (int r = 0; r < GROWS; r++) acc[r] = 0.f;
  #pragma unroll 3
  for (int k = 0; k < F_IN; k++) {
    float wv = W[k * C + j];
    #pragma unroll
    for (int r = 0; r < GROWS; r++) acc[r] += xr[r * FP + k] * wv;
  }
  #pragma unroll
  for (int r = 0; r < GROWS; r++) {
    int n = n0 + r;
    float v = fmaxf(acc[r] + b[j], 0.f);
    if (n < N) {
      H[(size_t)n * C + j] = v;
      Hb[(size_t)n * C + j] = f2bf(v);
    }
    xls[r * 132 + j] = v;
  }
  __syncthreads();
  int r = j >> 3, sub = j & 7;
  float sa0 = 0.f, sd0 = 0.f, sa1 = 0.f, sd1 = 0.f;
  for (int k = sub; k < C; k += 8) {
    float v = xls[r * 132 + k];
    sa0 += v * ws[k];      sd0 += v * wd[k];
    sa1 += v * ws[C + k];  sd1 += v * wd[C + k];
  }
  #pragma unroll
  for (int o = 4; o > 0; o >>= 1) {
    sa0 += __shfl_down(sa0, o); sd0 += __shfl_down(sd0, o);
    sa1 += __shfl_down(sa1, o); sd1 += __shfl_down(sd1, o);
  }
  int n = n0 + r;
  if (sub == 0 && n < N) {
    asrc[n * 2 + 0] = sa0; adst[n * 2 + 0] = sd0;
    asrc[n * 2 + 1] = sa1; adst[n * 2 + 1] = sd1;
  }
}

// ---- GAT edge softmax + input-space aggregate ------------------------------
// Agg[n, h*128 + k] (bf16) = (1/s_h) [ w_h*x[n,k] + sum_e alpha_e^h * x[r,k] ]
__global__ __launch_bounds__(256) void gat_agg_kernel(
    const unsigned* __restrict__ HbU, const float* __restrict__ asrc,
    const float* __restrict__ adst, const int* __restrict__ off,
    const int2* __restrict__ sedge, unsigned* __restrict__ AggU, int N) {
  __shared__ float2 lsc[4][MAXDEG];   // 4 KB
  int slot = threadIdx.x >> 6;
  int c = blockIdx.x * 4 + slot;
  if (c >= N) return;                 // wave-local LDS only, no barriers
  int l = threadIdx.x & 63;
  float2 adc = ((const float2*)adst)[c];
  float2 asc = ((const float2*)asrc)[c];
  int p0 = off[c], p1 = off[c + 1];
  int deg = p1 - p0;
  float e00 = asc.x + adc.x; e00 = e00 > 0.f ? e00 : 0.2f * e00;
  float e01 = asc.y + adc.y; e01 = e01 > 0.f ? e01 : 0.2f * e01;
  float m0 = e00, m1 = e01;
  for (int p = p0 + l; p < p1; p += 64) {
    int r = sedge[p].x;
    float2 av = ((const float2*)asrc)[r];
    float e0 = av.x + adc.x; e0 = e0 > 0.f ? e0 : 0.2f * e0;
    float e1 = av.y + adc.y; e1 = e1 > 0.f ? e1 : 0.2f * e1;
    int i = p - p0;
    if (i < MAXDEG) lsc[slot][i] = make_float2(e0, e1);
    m0 = fmaxf(m0, e0); m1 = fmaxf(m1, e1);
  }
  #pragma unroll
  for (int o = 32; o > 0; o >>= 1) {
    m0 = fmaxf(m0, __shfl_xor(m0, o));
    m1 = fmaxf(m1, __shfl_xor(m1, o));
  }
  int nl = deg < MAXDEG ? deg : MAXDEG;
  float s0 = 0.f, s1 = 0.f;
  for (int i = l; i < nl; i += 64) {
    float2 sc = lsc[slot][i];
    float a0 = __expf(sc.x - m0), a1 = __expf(sc.y - m1);
    lsc[slot][i] = make_float2(a0, a1);
    s0 += a0; s1 += a1;
  }
  for (int p = p0 + MAXDEG + l; p < p1; p += 64) {   // rare tail
    int r = sedge[p].x;
    float2 av = ((const float2*)asrc)[r];
    float e0 = av.x + adc.x; e0 = e0 > 0.f ? e0 : 0.2f * e0;
    float e1 = av.y + adc.y; e1 = e1 > 0.f ? e1 : 0.2f * e1;
    s0 += __expf(e0 - m0); s1 += __expf(e1 - m1);
  }
  #pragma unroll
  for (int o = 32; o > 0; o >>= 1) { s0 += __shfl_xor(s0, o); s1 += __shfl_xor(s1, o); }
  float w0 = __expf(e00 - m0), w1 = __expf(e01 - m1);
  s0 += w0; s1 += w1;
  float inv0 = 1.f / s0, inv1 = 1.f / s1;
  // aggregate input rows: lane l covers cols 2l, 2l+1 (one uint per row)
  unsigned uc = HbU[(unsigned)c * 64 + l];
  float a00 = w0 * bflo(uc), a01 = w0 * bfhi(uc);   // head0 lo/hi
  float a10 = w1 * bflo(uc), a11 = w1 * bfhi(uc);   // head1 lo/hi
  float b00 = 0.f, b01 = 0.f, b10 = 0.f, b11 = 0.f;
  int i = 0;
  for (; i + 8 <= nl; i += 8) {
    int r0 = sedge[p0 + i + 0].x, r1 = sedge[p0 + i + 1].x;
    int r2 = sedge[p0 + i + 2].x, r3 = sedge[p0 + i + 3].x;
    int r4 = sedge[p0 + i + 4].x, r5 = sedge[p0 + i + 5].x;
    int r6 = sedge[p0 + i + 6].x, r7 = sedge[p0 + i + 7].x;
    unsigned u0 = HbU[(unsigned)r0 * 64 + l];
    unsigned u1 = HbU[(unsigned)r1 * 64 + l];
    unsigned u2 = HbU[(unsigned)r2 * 64 + l];
    unsigned u3 = HbU[(unsigned)r3 * 64 + l];
    unsigned u4 = HbU[(unsigned)r4 * 64 + l];
    unsigned u5 = HbU[(unsigned)r5 * 64 + l];
    unsigned u6 = HbU[(unsigned)r6 * 64 + l];
    unsigned u7 = HbU[(unsigned)r7 * 64 + l];
    float2 f0 = lsc[slot][i + 0], f1 = lsc[slot][i + 1];
    float2 f2 = lsc[slot][i + 2], f3 = lsc[slot][i + 3];
    float2 f4 = lsc[slot][i + 4], f5 = lsc[slot][i + 5];
    float2 f6 = lsc[slot][i + 6], f7 = lsc[slot][i + 7];
    a00 += f0.x * bflo(u0); a01 += f0.x * bfhi(u0); a10 += f0.y * bflo(u0); a11 += f0.y * bfhi(u0);
    b00 += f1.x * bflo(u1); b01 += f1.x * bfhi(u1); b10 += f1.y * bflo(u1); b11 += f1.y * bfhi(u1);
    a00 += f2.x * bflo(u2); a01 += f2.x * bfhi(u2); a10 += f2.y * bflo(u2); a11 += f2.y * bfhi(u2);
    b00 += f3.x * bflo(u3); b01 += f3.x * bfhi(u3); b10 += f3.y * bflo(u3); b11 += f3.y * bfhi(u3);
    a00 += f4.x * bflo(u4); a01 += f4.x * bfhi(u4); a10 += f4.y * bflo(u4); a11 += f4.y * bfhi(u4);
    b00 += f5.x * bflo(u5); b01 += f5.x * bfhi(u5); b10 += f5.y * bflo(u5); b11 += f5.y * bfhi(u5);
    a00 += f6.x * bflo(u6); a01 += f6.x * bfhi(u6); a10 += f6.y * bflo(u6); a11 += f6.y * bfhi(u6);
    b00 += f7.x * bflo(u7); b01 += f7.x * bfhi(u7); b10 += f7.y * bflo(u7); b11 += f7.y * bfhi(u7);
  }
  for (; i < nl; i++) {
    int r0 = sedge[p0 + i].x;
    unsigned u0 = HbU[(unsigned)r0 * 64 + l];
    float2 f0 = lsc[slot][i];
    a00 += f0.x * bflo(u0); a01 += f0.x * bfhi(u0);
    a10 += f0.y * bflo(u0); a11 += f0.y * bfhi(u0);
  }
  for (int p = p0 + MAXDEG; p < p1; p++) {   // rare tail: recompute alpha
    int r = sedge[p].x;
    float2 av = ((const float2*)asrc)[r];
    float e0 = av.x + adc.x; e0 = e0 > 0.f ? e0 : 0.2f * e0;
    float e1 = av.y + adc.y; e1 = e1 > 0.f ? e1 : 0.2f * e1;
    float al0 = __expf(e0 - m0), al1 = __expf(e1 - m1);
    unsigned u0 = HbU[(unsigned)r * 64 + l];
    a00 += al0 * bflo(u0); a01 += al0 * bfhi(u0);
    a10 += al1 * bflo(u0); a11 += al1 * bfhi(u0);
  }
  AggU[(unsigned)c * 128 + l]      = pack2((a00 + b00) * inv0, (a01 + b01) * inv0);
  AggU[(unsigned)c * 128 + 64 + l] = pack2((a10 + b10) * inv1, (a11 + b11) * inv1);
}

// out = 0.5*(Agg @ Wp) + b  (+relu); K = 256 over (h,k)
__global__ void post_gemm_kernel(const unsigned* __restrict__ AggU, const float* __restrict__ Wp,
                                 const float* __restrict__ b, float* __restrict__ out,
                                 int relu, int N) {
  int n0 = blockIdx.x * GROWS;
  int j = threadIdx.x;   // 0..127
  __shared__ float als[GROWS * 260];   // 16.6 KB
  {
    const uint2* src = (const uint2*)(AggU + (size_t)n0 * 128);
    for (int t = j; t < GROWS * 64; t += 128) {   // 1024 uint2
      int row = t >> 6, cp = t & 63;
      uint2 u = (n0 + row < N) ? src[t] : make_uint2(0u, 0u);
      float* d = &als[row * 260 + cp * 4];
      d[0] = bflo(u.x); d[1] = bfhi(u.x); d[2] = bflo(u.y); d[3] = bfhi(u.y);
    }
  }
  __syncthreads();
  float acc[GROWS];
  #pragma unroll
  for (int r = 0; r < GROWS; r++) acc[r] = 0.f;
  #pragma unroll 2
  for (int k4 = 0; k4 < 256; k4 += 4) {
    float w0 = Wp[(k4 + 0) * C + j], w1 = Wp[(k4 + 1) * C + j];
    float w2 = Wp[(k4 + 2) * C + j], w3 = Wp[(k4 + 3) * C + j];
    #pragma unroll
    for (int r = 0; r < GROWS; r++) {
      float4 a = *(const float4*)&als[r * 260 + k4];
      acc[r] += a.x * w0 + a.y * w1 + a.z * w2 + a.w * w3;
    }
  }
  #pragma unroll
  for (int r = 0; r < GROWS; r++) {
    int n = n0 + r;
    if (n < N) {
      float v = 0.5f * acc[r] + b[j];
      if (relu) v = fmaxf(v, 0.f);
      out[(size_t)n * C + j] = v;
    }
  }
}

// ---- gated blend (+ optional bf16 copy & score dots for next layer) --------
__global__ void blend_kernel(const float* __restrict__ xt, const float* __restrict__ x,
                             const float* __restrict__ fc1W, const float* __restrict__ fc1b,
                             const float* __restrict__ fc2W, const float* __restrict__ fc2b,
                             const float* __restrict__ pb, float* __restrict__ out,
                             unsigned short* __restrict__ Hb2, const float* __restrict__ ws,
                             const float* __restrict__ wd, float* __restrict__ asrc,
                             float* __restrict__ adst, int dots, int N) {
  int n0 = blockIdx.x * GROWS;
  int j = threadIdx.x;   // 0..127
  __shared__ float xtr[GROWS * C];
  __shared__ float xr[GROWS * C];
  __shared__ float xls[GROWS * 132];
  {
    float4* a4 = (float4*)xtr;
    float4* b4 = (float4*)xr;
    const float4* xt4 = (const float4*)xt;
    const float4* x4 = (const float4*)x;
    for (int i = j; i < GROWS * C / 4; i += 128) {
      int n = n0 + (i * 4) / C;
      if (n < N) {
        a4[i] = xt4[n0 * (C / 4) + i];
        b4[i] = x4[n0 * (C / 4) + i];
      } else {
        a4[i] = make_float4(0.f, 0.f, 0.f, 0.f);
        b4[i] = make_float4(0.f, 0.f, 0.f, 0.f);
      }
    }
  }
  __syncthreads();
  float s1[GROWS], s2[GROWS];
  #pragma unroll
  for (int r = 0; r < GROWS; r++) { s1[r] = 0.f; s2[r] = 0.f; }
  #pragma unroll 2
  for (int k4 = 0; k4 < C; k4 += 4) {
    float w1a = fc1W[(k4 + 0) * C + j], w2a = fc2W[(k4 + 0) * C + j];
    float w1b = fc1W[(k4 + 1) * C + j], w2b = fc2W[(k4 + 1) * C + j];
    float w1c = fc1W[(k4 + 2) * C + j], w2c = fc2W[(k4 + 2) * C + j];
    float w1d = fc1W[(k4 + 3) * C + j], w2d = fc2W[(k4 + 3) * C + j];
    #pragma unroll
    for (int r = 0; r < GROWS; r++) {
      float4 t4 = *(const float4*)&xtr[r * C + k4];
      float4 x4 = *(const float4*)&xr[r * C + k4];
      s1[r] += t4.x * w1a + t4.y * w1b + t4.z * w1c + t4.w * w1d;
      s2[r] += x4.x * w2a + x4.y * w2b + x4.z * w2c + x4.w * w2d;
    }
  }
  float bb = fc1b[j] + fc2b[j] + pb[j];
  #pragma unroll
  for (int r = 0; r < GROWS; r++) {
    int n = n0 + r;
    float t = s1[r] + s2[r] + bb;
    float z = 1.f / (1.f + __expf(-t));
    float o = z * xtr[r * C + j] + (1.f - z) * xr[r * C + j];
    if (n < N) {
      out[(size_t)n * C + j] = o;
      if (dots) Hb2[(size_t)n * C + j] = f2bf(o);
    }
    xls[r * 132 + j] = o;
  }
  if (!dots) return;
  __syncthreads();
  int r = j >> 3, sub = j & 7;
  float sa0 = 0.f, sd0 = 0.f, sa1 = 0.f, sd1 = 0.f;
  for (int k = sub; k < C; k += 8) {
    float v = xls[r * 132 + k];
    sa0 += v * ws[k];      sd0 += v * wd[k];
    sa1 += v * ws[C + k];  sd1 += v * wd[C + k];
  }
  #pragma unroll
  for (int o = 4; o > 0; o >>= 1) {
    sa0 += __shfl_down(sa0, o); sd0 += __shfl_down(sd0, o);
    sa1 += __shfl_down(sa1, o); sd1 += __shfl_down(sd1, o);
  }
  int n = n0 + r;
  if (sub == 0 && n < N) {
    asrc[n * 2 + 0] = sa0; adst[n * 2 + 0] = sd0;
    asrc[n * 2 + 1] = sa1; adst[n * 2 + 1] = sd1;
  }
}

// ---- launch ----------------------------------------------------------------

extern "C" void kernel_launch(void* const* d_in, const int* in_sizes, int n_in,
                              void* d_out, int out_size, void* d_ws, size_t ws_size,
                              hipStream_t stream) {
  const float* x_in  = (const float*)d_in[0];
  const int*   ei    = (const int*)d_in[1];
  const float* ew    = (const float*)d_in[2];
  const float* gcn_W = (const float*)d_in[3];
  const float* gcn_b = (const float*)d_in[4];
  const float* g1_W  = (const float*)d_in[5];
  const float* g1_as = (const float*)d_in[6];
  const float* g1_ad = (const float*)d_in[7];
  const float* g1_b  = (const float*)d_in[8];
  const float* g2_W  = (const float*)d_in[9];
  const float* g2_as = (const float*)d_in[10];
  const float* g2_ad = (const float*)d_in[11];
  const float* g2_b  = (const float*)d_in[12];
  const float* fc1_W = (const float*)d_in[13];
  const float* fc1_b = (const float*)d_in[14];
  const float* fc2_W = (const float*)d_in[15];
  const float* fc2_b = (const float*)d_in[16];
  const float* pb    = (const float*)d_in[17];

  const int N = in_sizes[0] / F_IN;
  const int E = in_sizes[2];
  const int* row = ei;
  const int* col = ei + E;

  char* ws = (char*)d_ws;
  size_t o = 0;
  auto alloc = [&](size_t bytes) -> void* {
    void* p = ws + o;
    o += (bytes + 255) & ~(size_t)255;
    return p;
  };
  int*   cnt   = (int*)alloc((size_t)(N + 1) * 4);
  int*   cur   = (int*)alloc((size_t)N * 4);
  float* deg   = (float*)alloc((size_t)N * 4);
  size_t zero_bytes = o;                     // cnt+cur+deg at ws start
  int*   off   = (int*)alloc((size_t)(N + 1) * 4);
  float* dinv  = (float*)alloc((size_t)N * 4);
  int*   bsum  = (int*)alloc(256 * 4);
  int2*  sedge = (int2*)alloc((size_t)E * 8);
  float* attv  = (float*)alloc(1024 * 4);                 // ws1,wd1,ws2,wd2
  float* Wp1   = (float*)alloc((size_t)256 * C * 4);
  float* Wp2   = (float*)alloc((size_t)256 * C * 4);
  float* asrc  = (float*)alloc((size_t)N * 2 * 4);
  float* adst  = (float*)alloc((size_t)N * 2 * 4);
  unsigned* X36U = (unsigned*)alloc((size_t)N * (FP / 2) * 4);   // bf16 [N,36]
  float* Xagg  = (float*)alloc((size_t)N * FP * 4);
  float* H     = (float*)alloc((size_t)N * C * 4);        // gcn out
  unsigned short* Hb  = (unsigned short*)alloc((size_t)N * C * 2);
  unsigned* AggU = (unsigned*)alloc((size_t)N * 128 * 4); // bf16 [N,2,128]
  float* XT    = (float*)alloc((size_t)N * C * 4);        // gat out
  float* H2    = (float*)alloc((size_t)N * C * 4);        // blend1 out
  unsigned short* Hb2 = (unsigned short*)alloc((size_t)N * C * 2);
  (void)ws_size; (void)n_in; (void)out_size;

  float* ws1 = attv + 0,   *wd1 = attv + 256;
  float* ws2 = attv + 512, *wd2 = attv + 768;

  hipMemsetAsync(d_ws, 0, zero_bytes, stream);

  const int tb = 256;
  const int nP = N + 1;
  const int nb = (nP + 1023) / 1024;

  // parameter prep (input-only deps)
  prep_dots_kernel<<<4, 256, 0, stream>>>(g1_W, g1_as, g1_ad, g2_W, g2_as, g2_ad, attv);
  prep_repack_kernel<<<256, 256, 0, stream>>>(g1_W, g2_W, Wp1, Wp2);
  convert_x_kernel<<<(N * (FP / 2) + tb - 1) / tb, tb, 0, stream>>>(x_in, X36U, N);

  // CSR build
  count_kernel<<<(E + tb - 1) / tb, tb, 0, stream>>>(col, ew, cnt, deg, E);
  scan1_kernel<<<nb, 256, 0, stream>>>(cnt, off, bsum, nP);
  scan2_kernel<<<1, 256, 0, stream>>>(bsum, nb);
  scan3_dinv_kernel<<<(nP + tb - 1) / tb, tb, 0, stream>>>(off, bsum, deg, dinv, nP, N);
  scatter_kernel<<<(E + tb - 1) / tb, tb, 0, stream>>>(row, col, ew, off, dinv, cur, sedge, E);

  // GCN: aggregate 33-dim inputs, then project (+relu, +layer1 score dots)
  gcn_agg33_kernel<<<(N + 3) / 4, 256, 0, stream>>>(X36U, off, sedge, dinv, Xagg, N);
  gemm36_kernel<<<(N + GROWS - 1) / GROWS, C, 0, stream>>>(Xagg, gcn_W, gcn_b, ws1, wd1,
                                                           H, Hb, asrc, adst, N);

  // GAT layer 1: softmax+aggregate in input space, project, blend (+layer2 dots)
  gat_agg_kernel<<<(N + 3) / 4, 256, 0, stream>>>((const unsigned*)Hb, asrc, adst, off, sedge, AggU, N);
  post_gemm_kernel<<<(N + GROWS - 1) / GROWS, C, 0, stream>>>(AggU, Wp1, g1_b, XT, 1, N);
  blend_kernel<<<(N + GROWS - 1) / GROWS, C, 0, stream>>>(XT, H, fc1_W, fc1_b, fc2_W, fc2_b, pb,
                                                          H2, Hb2, ws2, wd2, asrc, adst, 1, N);

  // GAT layer 2 + final blend into d_out
  gat_agg_kernel<<<(N + 3) / 4, 256, 0, stream>>>((const unsigned*)Hb2, asrc, adst, off, sedge, AggU, N);
  post_gemm_kernel<<<(N + GROWS - 1) / GROWS, C, 0, stream>>>(AggU, Wp2, g2_b, XT, 0, N);
  blend_kernel<<<(N + GROWS - 1) / GROWS, C, 0, stream>>>(XT, H2, fc1_W, fc1_b, fc2_W, fc2_b, pb,
                                                          (float*)d_out, (unsigned short*)0,
                                                          ws2, wd2, asrc, adst, 0, N);
}